// Round 1
// baseline (1180.612 us; speedup 1.0000x reference)
//
#include <hip/hip_runtime.h>
#include <cstdint>
#include <cstddef>

#define T_TOK 2048
#define HID   2048
#define NEXP  16
#define INTER 768
#define TOPK  2
#define CAP   1024   // max pairs per expert (mean 256, binomial; 1024 is unreachable)

// ---------------------------------------------------------------------------
// Workspace layout (bytes):
//   [0,64)                      counts[NEXP]
//   [1024, 1024+64K)            pair_tk[NEXP*CAP]   (tk = t*TOPK + k)
//   [1024+64K, 1024+128K)       pair_w [NEXP*CAP]
//   [1024+128K, +12.6MB)        hbuf[T_TOK*TOPK*INTER]  (silu(gate)*up per pair)
// ---------------------------------------------------------------------------

__global__ __launch_bounds__(256)
void route_kernel(const int* __restrict__ idx, const float* __restrict__ wts,
                  int* __restrict__ counts, int* __restrict__ pair_tk,
                  float* __restrict__ pair_w) {
    int p = blockIdx.x * blockDim.x + threadIdx.x;   // pair id = t*TOPK + k
    if (p >= T_TOK * TOPK) return;
    int e = idx[p];
    int pos = atomicAdd(&counts[e], 1);
    if (pos < CAP) {
        pair_tk[e * CAP + pos] = p;
        pair_w [e * CAP + pos] = wts[p];
    }
}

// stage1: for expert e, tokens tile 64 x I-cols tile 64, K = HID.
// computes gate = hs . gup[e][n], up = hs . gup[e][n+INTER]; h = silu(g)*u
__global__ __launch_bounds__(256)
void stage1_kernel(const float* __restrict__ hs, const float* __restrict__ gup,
                   const int* __restrict__ counts, const int* __restrict__ pair_tk,
                   float* __restrict__ hbuf) {
    __shared__ float As[32][65];   // [k][m], pad 65: conflict-free scatter/reads
    __shared__ float Bg[32][65];
    __shared__ float Bu[32][65];

    const int e   = blockIdx.z;
    const int cnt = min(counts[e], CAP);
    const int m0  = blockIdx.y * 64;
    if (m0 >= cnt) return;                      // uniform early-exit (before any sync)
    const int n0  = blockIdx.x * 64;

    const int tid = threadIdx.x;
    const int tx  = tid & 15, ty = tid >> 4;
    const float* gupe = gup + (size_t)e * (2 * INTER) * HID;

    // A-load mapping: each thread loads float4 at (row, kk) twice
    const int rowA = tid >> 3;        // 0..31
    const int kkA  = (tid & 7) * 4;   // 0..28
    int  tkrow[2]; bool vrow[2];
    #pragma unroll
    for (int it = 0; it < 2; ++it) {
        int slot = m0 + rowA + 32 * it;
        vrow[it]  = slot < cnt;
        tkrow[it] = vrow[it] ? pair_tk[e * CAP + slot] : 0;
    }

    float accg[4][4] = {{0.f}}, accu[4][4] = {{0.f}};

    for (int k0 = 0; k0 < HID; k0 += 32) {
        #pragma unroll
        for (int it = 0; it < 2; ++it) {
            int r = rowA + 32 * it;
            float4 v = make_float4(0.f, 0.f, 0.f, 0.f);
            if (vrow[it])
                v = *(const float4*)(hs + (size_t)(tkrow[it] >> 1) * HID + k0 + kkA);
            As[kkA][r] = v.x; As[kkA+1][r] = v.y; As[kkA+2][r] = v.z; As[kkA+3][r] = v.w;

            float4 vg = *(const float4*)(gupe + (size_t)(n0 + r) * HID + k0 + kkA);
            float4 vu = *(const float4*)(gupe + (size_t)(n0 + r + INTER) * HID + k0 + kkA);
            Bg[kkA][r] = vg.x; Bg[kkA+1][r] = vg.y; Bg[kkA+2][r] = vg.z; Bg[kkA+3][r] = vg.w;
            Bu[kkA][r] = vu.x; Bu[kkA+1][r] = vu.y; Bu[kkA+2][r] = vu.z; Bu[kkA+3][r] = vu.w;
        }
        __syncthreads();
        #pragma unroll
        for (int kk = 0; kk < 32; ++kk) {
            float a[4], bg[4], bu[4];
            #pragma unroll
            for (int i = 0; i < 4; ++i) a[i] = As[kk][ty + 16 * i];
            #pragma unroll
            for (int j = 0; j < 4; ++j) { bg[j] = Bg[kk][tx + 16 * j]; bu[j] = Bu[kk][tx + 16 * j]; }
            #pragma unroll
            for (int i = 0; i < 4; ++i)
                #pragma unroll
                for (int j = 0; j < 4; ++j) {
                    accg[i][j] = fmaf(a[i], bg[j], accg[i][j]);
                    accu[i][j] = fmaf(a[i], bu[j], accu[i][j]);
                }
        }
        __syncthreads();
    }

    #pragma unroll
    for (int i = 0; i < 4; ++i) {
        int slot = m0 + ty + 16 * i;
        if (slot >= cnt) continue;
        int tk = pair_tk[e * CAP + slot];
        float* hrow = hbuf + (size_t)tk * INTER + n0;
        #pragma unroll
        for (int j = 0; j < 4; ++j) {
            float g = accg[i][j], u = accu[i][j];
            float s = g / (1.f + __expf(-g));    // silu
            hrow[tx + 16 * j] = s * u;
        }
    }
}

// stage2: y[pair, hcol] = h[pair,:] . down[e][hcol,:]; out[t] += w * y (atomic)
__global__ __launch_bounds__(256)
void stage2_kernel(const float* __restrict__ hbuf, const float* __restrict__ dwn,
                   const int* __restrict__ counts, const int* __restrict__ pair_tk,
                   const float* __restrict__ pair_w, float* __restrict__ out) {
    __shared__ float As[32][65];
    __shared__ float Bs[32][133];

    const int e   = blockIdx.z;
    const int cnt = min(counts[e], CAP);
    const int m0  = blockIdx.y * 64;
    if (m0 >= cnt) return;
    const int n0  = blockIdx.x * 128;

    const int tid = threadIdx.x;
    const int tx  = tid & 15, ty = tid >> 4;
    const float* de = dwn + (size_t)e * HID * INTER;

    const int rowA = tid >> 3;
    const int kkA  = (tid & 7) * 4;
    int  tkrow[2]; bool vrow[2];
    #pragma unroll
    for (int it = 0; it < 2; ++it) {
        int slot = m0 + rowA + 32 * it;
        vrow[it]  = slot < cnt;
        tkrow[it] = vrow[it] ? pair_tk[e * CAP + slot] : 0;
    }

    float acc[4][8] = {{0.f}};

    for (int k0 = 0; k0 < INTER; k0 += 32) {
        #pragma unroll
        for (int it = 0; it < 2; ++it) {
            int r = rowA + 32 * it;
            float4 v = make_float4(0.f, 0.f, 0.f, 0.f);
            if (vrow[it])
                v = *(const float4*)(hbuf + (size_t)tkrow[it] * INTER + k0 + kkA);
            As[kkA][r] = v.x; As[kkA+1][r] = v.y; As[kkA+2][r] = v.z; As[kkA+3][r] = v.w;
        }
        #pragma unroll
        for (int it = 0; it < 4; ++it) {
            int n = rowA + 32 * it;   // 0..127
            float4 vb = *(const float4*)(de + (size_t)(n0 + n) * INTER + k0 + kkA);
            Bs[kkA][n] = vb.x; Bs[kkA+1][n] = vb.y; Bs[kkA+2][n] = vb.z; Bs[kkA+3][n] = vb.w;
        }
        __syncthreads();
        #pragma unroll
        for (int kk = 0; kk < 32; ++kk) {
            float a[4], b[8];
            #pragma unroll
            for (int i = 0; i < 4; ++i) a[i] = As[kk][ty + 16 * i];
            #pragma unroll
            for (int j = 0; j < 8; ++j) b[j] = Bs[kk][tx + 16 * j];
            #pragma unroll
            for (int i = 0; i < 4; ++i)
                #pragma unroll
                for (int j = 0; j < 8; ++j)
                    acc[i][j] = fmaf(a[i], b[j], acc[i][j]);
        }
        __syncthreads();
    }

    #pragma unroll
    for (int i = 0; i < 4; ++i) {
        int slot = m0 + ty + 16 * i;
        if (slot >= cnt) continue;
        int tk = pair_tk[e * CAP + slot];
        int t  = tk >> 1;                       // TOPK == 2
        float wp = pair_w[e * CAP + slot];
        float* orow = out + (size_t)t * HID + n0;
        #pragma unroll
        for (int j = 0; j < 8; ++j)
            atomicAdd(&orow[tx + 16 * j], wp * acc[i][j]);
    }
}

extern "C" void kernel_launch(void* const* d_in, const int* in_sizes, int n_in,
                              void* d_out, int out_size, void* d_ws, size_t ws_size,
                              hipStream_t stream) {
    const float* hs  = (const float*)d_in[0];   // (T, H)
    const int*   idx = (const int*)  d_in[1];   // (T, K) int32
    const float* wts = (const float*)d_in[2];   // (T, K)
    const float* gup = (const float*)d_in[3];   // (E, 2I, H)
    const float* dwn = (const float*)d_in[4];   // (E, H, I)
    float* out = (float*)d_out;                 // (T, H)

    char* ws = (char*)d_ws;
    int*   counts  = (int*)ws;
    int*   pair_tk = (int*)(ws + 1024);
    float* pair_w  = (float*)(ws + 1024 + NEXP * CAP * 4);
    float* hbuf    = (float*)(ws + 1024 + 2 * NEXP * CAP * 4);

    hipMemsetAsync(counts, 0, NEXP * sizeof(int), stream);
    hipMemsetAsync(out, 0, (size_t)T_TOK * HID * sizeof(float), stream);

    route_kernel<<<(T_TOK * TOPK + 255) / 256, 256, 0, stream>>>(idx, wts, counts, pair_tk, pair_w);
    stage1_kernel<<<dim3(INTER / 64, CAP / 64, NEXP), 256, 0, stream>>>(hs, gup, counts, pair_tk, hbuf);
    stage2_kernel<<<dim3(HID / 128, CAP / 64, NEXP), 256, 0, stream>>>(hbuf, dwn, counts, pair_tk, pair_w, out);
}

// Round 2
// 781.263 us; speedup vs baseline: 1.5112x; 1.5112x over previous
//
#include <hip/hip_runtime.h>
#include <hip/hip_bf16.h>
#include <cstdint>
#include <cstddef>

#define T_TOK 2048
#define HID   2048
#define NEXP  16
#define INTER 768
#define TOPK  2
#define CAP   1024

using short8 = __attribute__((ext_vector_type(8))) short;
using f32x16 = __attribute__((ext_vector_type(16))) float;

#define MFMA(a,b,c) __builtin_amdgcn_mfma_f32_32x32x16_bf16((a),(b),(c),0,0,0)

__device__ inline ushort bf16_bits(float x) {
    __hip_bfloat16 b = __float2bfloat16(x);
    union { __hip_bfloat16 b; ushort u; } cv; cv.b = b; return cv.u;
}
__device__ inline void split1(float x, ushort& h, ushort& l) {
    ushort hb = bf16_bits(x);
    float hf = __uint_as_float(((uint32_t)hb) << 16);
    h = hb;
    l = bf16_bits(x - hf);
}

// Fragment-major LDS stash: element (row, kk) of a [rows][64] bf16 tile goes to
// frag f = (row>>5)*4 + (kk>>4), lane = (row&31) + 32*((kk>>3)&1), j = kk&7.
// Each fragment = 512 ushorts = 1KB; frag read is lane*16B contiguous -> conflict-free.
__device__ inline void stash4(ushort* __restrict__ Hi, ushort* __restrict__ Lo,
                              int row, int kk, float4 v) {
    int f    = (row >> 5) * 4 + (kk >> 4);
    int ln   = (row & 31) + (((kk >> 3) & 1) << 5);
    int idx  = (f << 9) + (ln << 3) + (kk & 7);
    ushort h0,l0,h1,l1,h2,l2,h3,l3;
    split1(v.x, h0, l0); split1(v.y, h1, l1); split1(v.z, h2, l2); split1(v.w, h3, l3);
    *reinterpret_cast<ushort4*>(&Hi[idx]) = make_ushort4(h0, h1, h2, h3);
    *reinterpret_cast<ushort4*>(&Lo[idx]) = make_ushort4(l0, l1, l2, l3);
}

__global__ __launch_bounds__(256)
void route_kernel(const int* __restrict__ idx, const float* __restrict__ wts,
                  int* __restrict__ counts, int* __restrict__ pair_tk,
                  float* __restrict__ pair_w) {
    int p = blockIdx.x * blockDim.x + threadIdx.x;
    if (p >= T_TOK * TOPK) return;
    int e = idx[p];
    int pos = atomicAdd(&counts[e], 1);
    if (pos < CAP) {
        pair_tk[e * CAP + pos] = p;
        pair_w [e * CAP + pos] = wts[p];
    }
}

// stage1: h = silu(hs.Wg) * (hs.Wu), hi/lo split bf16 MFMA, BM=64 BN_h=64 BK=64.
__global__ __launch_bounds__(128, 2)
void stage1_kernel(const float* __restrict__ hs, const float* __restrict__ gup,
                   const int* __restrict__ counts, const int* __restrict__ pair_tk,
                   float* __restrict__ hbuf) {
    __shared__ ushort Ahi[64*64], Alo[64*64];
    __shared__ ushort Bhi[128*64], Blo[128*64];
    __shared__ int s_tk[64];

    const int e   = blockIdx.z;
    const int cnt = min(counts[e], CAP);
    const int m0  = blockIdx.y * 64;
    if (m0 >= cnt) return;
    const int n0  = blockIdx.x * 64;

    const int tid  = threadIdx.x;       // 0..127
    const int lane = tid & 63;
    const int wn   = tid >> 6;          // wave id: n-col half

    if (tid < 64) {
        int slot = m0 + tid;
        s_tk[tid] = (slot < cnt) ? pair_tk[e * CAP + slot] : -1;
    }
    __syncthreads();

    const float* gupe = gup + (size_t)e * (2 * INTER) * HID;

    const int arow = tid >> 1;
    const int akh  = (tid & 1) * 32;
    const int tkA  = s_tk[arow];
    const bool avalid = (tkA >= 0);
    const float* asrc = hs + (size_t)(avalid ? (tkA >> 1) : 0) * HID;

    const int brow = tid;               // 0..127: 0-63 gate cols, 64-127 up cols
    const float* bsrc = gupe + (size_t)((brow < 64) ? (n0 + brow)
                                                    : (INTER + n0 + brow - 64)) * HID;

    f32x16 accg[2], accu[2];
    #pragma unroll
    for (int mi = 0; mi < 2; ++mi)
        #pragma unroll
        for (int r = 0; r < 16; ++r) { accg[mi][r] = 0.f; accu[mi][r] = 0.f; }

    for (int k0 = 0; k0 < HID; k0 += 64) {
        float4 av[8];
        #pragma unroll
        for (int q = 0; q < 8; ++q) {
            av[q] = *(const float4*)(asrc + k0 + akh + 4 * q);
            if (!avalid) av[q] = make_float4(0.f, 0.f, 0.f, 0.f);
        }
        float4 bv[16];
        #pragma unroll
        for (int q = 0; q < 16; ++q)
            bv[q] = *(const float4*)(bsrc + k0 + 4 * q);

        #pragma unroll
        for (int q = 0; q < 8; ++q)  stash4(Ahi, Alo, arow, akh + 4 * q, av[q]);
        #pragma unroll
        for (int q = 0; q < 16; ++q) stash4(Bhi, Blo, brow, 4 * q, bv[q]);
        __syncthreads();

        const int ro = lane << 3;
        #pragma unroll
        for (int kg = 0; kg < 4; ++kg) {
            short8 ah0 = *(const short8*)&Ahi[((0 * 4 + kg) << 9) + ro];
            short8 ah1 = *(const short8*)&Ahi[((1 * 4 + kg) << 9) + ro];
            short8 al0 = *(const short8*)&Alo[((0 * 4 + kg) << 9) + ro];
            short8 al1 = *(const short8*)&Alo[((1 * 4 + kg) << 9) + ro];
            short8 bgh = *(const short8*)&Bhi[(((wn)     * 4 + kg) << 9) + ro];
            short8 bgl = *(const short8*)&Blo[(((wn)     * 4 + kg) << 9) + ro];
            short8 buh = *(const short8*)&Bhi[(((2 + wn) * 4 + kg) << 9) + ro];
            short8 bul = *(const short8*)&Blo[(((2 + wn) * 4 + kg) << 9) + ro];
            accg[0] = MFMA(ah0, bgh, accg[0]);
            accg[0] = MFMA(ah0, bgl, accg[0]);
            accg[0] = MFMA(al0, bgh, accg[0]);
            accg[1] = MFMA(ah1, bgh, accg[1]);
            accg[1] = MFMA(ah1, bgl, accg[1]);
            accg[1] = MFMA(al1, bgh, accg[1]);
            accu[0] = MFMA(ah0, buh, accu[0]);
            accu[0] = MFMA(ah0, bul, accu[0]);
            accu[0] = MFMA(al0, buh, accu[0]);
            accu[1] = MFMA(ah1, buh, accu[1]);
            accu[1] = MFMA(ah1, bul, accu[1]);
            accu[1] = MFMA(al1, buh, accu[1]);
        }
        __syncthreads();
    }

    const int crhi = (lane >> 5) * 4;
    const int col  = n0 + wn * 32 + (lane & 31);
    #pragma unroll
    for (int mi = 0; mi < 2; ++mi) {
        #pragma unroll
        for (int r = 0; r < 16; ++r) {
            int row  = (r & 3) + 8 * (r >> 2) + crhi;
            int slot = m0 + mi * 32 + row;
            if (slot < cnt) {
                int tk  = s_tk[mi * 32 + row];
                float g = accg[mi][r], u = accu[mi][r];
                float s = g / (1.f + __expf(-g));
                hbuf[(size_t)tk * INTER + col] = s * u;
            }
        }
    }
}

// stage2: out[t] += w * (h . down[e]^T), BM=64 BN=128 BK=64.
__global__ __launch_bounds__(128, 2)
void stage2_kernel(const float* __restrict__ hbuf, const float* __restrict__ dwn,
                   const int* __restrict__ counts, const int* __restrict__ pair_tk,
                   const float* __restrict__ pair_w, float* __restrict__ out) {
    __shared__ ushort Ahi[64*64], Alo[64*64];
    __shared__ ushort Bhi[128*64], Blo[128*64];
    __shared__ int   s_tk[64];
    __shared__ float s_w[64];

    const int e   = blockIdx.z;
    const int cnt = min(counts[e], CAP);
    const int m0  = blockIdx.y * 64;
    if (m0 >= cnt) return;
    const int n0  = blockIdx.x * 128;

    const int tid  = threadIdx.x;
    const int lane = tid & 63;
    const int wn   = tid >> 6;

    if (tid < 64) {
        int slot = m0 + tid;
        bool v = slot < cnt;
        s_tk[tid] = v ? pair_tk[e * CAP + slot] : -1;
        s_w[tid]  = v ? pair_w [e * CAP + slot] : 0.f;
    }
    __syncthreads();

    const int arow = tid >> 1;
    const int akh  = (tid & 1) * 32;
    const int tkA  = s_tk[arow];
    const bool avalid = (tkA >= 0);
    const float* asrc = hbuf + (size_t)(avalid ? tkA : 0) * INTER;

    const int brow = tid;               // 0..127 -> out cols n0+brow
    const float* bsrc = dwn + (size_t)e * HID * INTER + (size_t)(n0 + brow) * INTER;

    f32x16 acc[2][2];
    #pragma unroll
    for (int mi = 0; mi < 2; ++mi)
        #pragma unroll
        for (int ni = 0; ni < 2; ++ni)
            #pragma unroll
            for (int r = 0; r < 16; ++r) acc[mi][ni][r] = 0.f;

    for (int k0 = 0; k0 < INTER; k0 += 64) {
        float4 av[8];
        #pragma unroll
        for (int q = 0; q < 8; ++q) {
            av[q] = *(const float4*)(asrc + k0 + akh + 4 * q);
            if (!avalid) av[q] = make_float4(0.f, 0.f, 0.f, 0.f);
        }
        float4 bv[16];
        #pragma unroll
        for (int q = 0; q < 16; ++q)
            bv[q] = *(const float4*)(bsrc + k0 + 4 * q);

        #pragma unroll
        for (int q = 0; q < 8; ++q)  stash4(Ahi, Alo, arow, akh + 4 * q, av[q]);
        #pragma unroll
        for (int q = 0; q < 16; ++q) stash4(Bhi, Blo, brow, 4 * q, bv[q]);
        __syncthreads();

        const int ro = lane << 3;
        #pragma unroll
        for (int kg = 0; kg < 4; ++kg) {
            short8 ah0 = *(const short8*)&Ahi[((0 * 4 + kg) << 9) + ro];
            short8 ah1 = *(const short8*)&Ahi[((1 * 4 + kg) << 9) + ro];
            short8 al0 = *(const short8*)&Alo[((0 * 4 + kg) << 9) + ro];
            short8 al1 = *(const short8*)&Alo[((1 * 4 + kg) << 9) + ro];
            #pragma unroll
            for (int ni = 0; ni < 2; ++ni) {
                int nb = wn * 2 + ni;
                short8 bh = *(const short8*)&Bhi[((nb * 4 + kg) << 9) + ro];
                short8 bl = *(const short8*)&Blo[((nb * 4 + kg) << 9) + ro];
                acc[0][ni] = MFMA(ah0, bh, acc[0][ni]);
                acc[0][ni] = MFMA(ah0, bl, acc[0][ni]);
                acc[0][ni] = MFMA(al0, bh, acc[0][ni]);
                acc[1][ni] = MFMA(ah1, bh, acc[1][ni]);
                acc[1][ni] = MFMA(ah1, bl, acc[1][ni]);
                acc[1][ni] = MFMA(al1, bh, acc[1][ni]);
            }
        }
        __syncthreads();
    }

    const int crhi = (lane >> 5) * 4;
    #pragma unroll
    for (int mi = 0; mi < 2; ++mi) {
        #pragma unroll
        for (int r = 0; r < 16; ++r) {
            int row  = (r & 3) + 8 * (r >> 2) + crhi;
            int slot = m0 + mi * 32 + row;
            if (slot < cnt) {
                int   t = s_tk[mi * 32 + row] >> 1;   // TOPK == 2
                float w = s_w[mi * 32 + row];
                #pragma unroll
                for (int ni = 0; ni < 2; ++ni) {
                    int col = n0 + (wn * 2 + ni) * 32 + (lane & 31);
                    atomicAdd(&out[(size_t)t * HID + col], w * acc[mi][ni][r]);
                }
            }
        }
    }
}

extern "C" void kernel_launch(void* const* d_in, const int* in_sizes, int n_in,
                              void* d_out, int out_size, void* d_ws, size_t ws_size,
                              hipStream_t stream) {
    const float* hs  = (const float*)d_in[0];
    const int*   idx = (const int*)  d_in[1];
    const float* wts = (const float*)d_in[2];
    const float* gup = (const float*)d_in[3];
    const float* dwn = (const float*)d_in[4];
    float* out = (float*)d_out;

    char* ws = (char*)d_ws;
    int*   counts  = (int*)ws;
    int*   pair_tk = (int*)(ws + 1024);
    float* pair_w  = (float*)(ws + 1024 + NEXP * CAP * 4);
    float* hbuf    = (float*)(ws + 1024 + 2 * NEXP * CAP * 4);

    hipMemsetAsync(counts, 0, NEXP * sizeof(int), stream);
    hipMemsetAsync(out, 0, (size_t)T_TOK * HID * sizeof(float), stream);

    route_kernel<<<(T_TOK * TOPK + 255) / 256, 256, 0, stream>>>(idx, wts, counts, pair_tk, pair_w);
    stage1_kernel<<<dim3(INTER / 64, CAP / 64, NEXP), 128, 0, stream>>>(hs, gup, counts, pair_tk, hbuf);
    stage2_kernel<<<dim3(HID / 128, CAP / 64, NEXP), 128, 0, stream>>>(hbuf, dwn, counts, pair_tk, pair_w, out);
}

// Round 4
// 638.673 us; speedup vs baseline: 1.8485x; 1.2233x over previous
//
#include <hip/hip_runtime.h>
#include <hip/hip_bf16.h>
#include <cstdint>
#include <cstddef>

#define T_TOK 2048
#define HID   2048
#define NEXP  16
#define INTER 768
#define TOPK  2
#define CAP   1024
#define MBLK  8      // grid covers 8*64=512 slots/expert (mean 256, ~16 sigma safe)

using short8  = __attribute__((ext_vector_type(8))) short;
using f32x16  = __attribute__((ext_vector_type(16))) float;

#define MFMA(a,b,c) __builtin_amdgcn_mfma_f32_32x32x16_bf16((a),(b),(c),0,0,0)

__device__ inline ushort bf16h(float x) {
    union { __hip_bfloat16 b; ushort u; } cv; cv.b = __float2bfloat16(x); return cv.u;
}
__device__ inline void split8(float4 a, float4 b, short8& h, short8& l) {
    float v[8] = {a.x,a.y,a.z,a.w,b.x,b.y,b.z,b.w};
    #pragma unroll
    for (int j = 0; j < 8; ++j) {
        ushort hb = bf16h(v[j]);
        float hf = __uint_as_float(((uint32_t)hb) << 16);
        h[j] = (short)hb;
        l[j] = (short)bf16h(v[j] - hf);
    }
}

__global__ __launch_bounds__(256)
void route_kernel(const int* __restrict__ idx, const float* __restrict__ wts,
                  int* __restrict__ counts, int* __restrict__ pair_tk,
                  float* __restrict__ pair_w) {
    int p = blockIdx.x * blockDim.x + threadIdx.x;
    if (p >= T_TOK * TOPK) return;
    int e = idx[p];
    int pos = atomicAdd(&counts[e], 1);
    if (pos < CAP) {
        pair_tk[e * CAP + pos] = p;
        pair_w [e * CAP + pos] = wts[p];
    }
}

// stage1: gu[tk][0:768]=gate partial, gu[tk][768:1536]=up partial (fp32 atomics, K-split=2)
// BM=64, BNpair=128 (128 gate + 128 up cols), BK=32. 4 waves, wave = 64 x 32pair.
__global__ __launch_bounds__(256)
void stage1_kernel(const float* __restrict__ hs, const float* __restrict__ gup,
                   const int* __restrict__ counts, const int* __restrict__ pair_tk,
                   float* __restrict__ gu) {
    __shared__ ushort Ahi[4*512], Alo[4*512];    // 64x32, 4 frags/plane
    __shared__ ushort Bhi[16*512], Blo[16*512];  // 256x32, 16 frags/plane
    __shared__ int s_tk[64];

    const int e  = blockIdx.z >> 1;
    const int ks = blockIdx.z & 1;
    const int cnt = min(counts[e], CAP);
    const int m0  = blockIdx.y * 64;
    if (m0 >= cnt) return;
    const int n0  = blockIdx.x * 128;

    const int tid = threadIdx.x, lane = tid & 63, w = tid >> 6;
    if (tid < 64) s_tk[tid] = pair_tk[e*CAP + min(m0+tid, cnt-1)];
    __syncthreads();

    // staging roles: A: (row ar, k-octet aq); B: row br, 4 octets
    const int ar = tid & 63, aq = tid >> 6;
    const float* asrc = hs + (size_t)(s_tk[ar] >> 1)*HID + ks*1024 + aq*8;
    const int br = tid;
    const float* bsrc = gup + (size_t)e*(2*INTER)*HID
                      + (size_t)((br < 128) ? (n0+br) : (INTER + n0 + br - 128))*HID
                      + ks*1024;

    const int fA  = (ar>>5)*2 + (aq>>1);
    const int lnA = (ar&31) + 32*(aq&1);
    const int rgB = br >> 5, lnB = br & 31;

    f32x16 accg[2], accu[2];
    #pragma unroll
    for (int i=0;i<16;++i){ accg[0][i]=0.f; accg[1][i]=0.f; accu[0][i]=0.f; accu[1][i]=0.f; }

    float4 a0c,a1c,bvc[8], a0n,a1n,bvn[8];
    a0c = *(const float4*)(asrc + 0);
    a1c = *(const float4*)(asrc + 4);
    #pragma unroll
    for (int q=0;q<8;++q) bvc[q] = *(const float4*)(bsrc + 4*q);

#define S1_BODY(A0,A1,BV,A0N,A1N,BVN,KST)                                        \
    {                                                                            \
        __syncthreads();                                                         \
        { short8 h,l; split8(A0,A1,h,l);                                         \
          *(short8*)&Ahi[(fA<<9)+(lnA<<3)] = h;                                  \
          *(short8*)&Alo[(fA<<9)+(lnA<<3)] = l; }                                \
        _Pragma("unroll")                                                        \
        for (int o=0;o<4;++o) { short8 h,l; split8(BV[2*o],BV[2*o+1],h,l);       \
          int f = rgB*2 + (o>>1); int ln = lnB + 32*(o&1);                       \
          *(short8*)&Bhi[(f<<9)+(ln<<3)] = h;                                    \
          *(short8*)&Blo[(f<<9)+(ln<<3)] = l; }                                  \
        if ((KST)+1 < 32) {                                                      \
            int ko = ((KST)+1)*32;                                               \
            A0N = *(const float4*)(asrc + ko);                                   \
            A1N = *(const float4*)(asrc + ko + 4);                               \
            _Pragma("unroll")                                                    \
            for (int q=0;q<8;++q) BVN[q] = *(const float4*)(bsrc + ko + 4*q);    \
        }                                                                        \
        __syncthreads();                                                         \
        const int ro = lane << 3;                                                \
        _Pragma("unroll")                                                        \
        for (int kf=0;kf<2;++kf) {                                               \
            short8 ah0 = *(const short8*)&Ahi[((0*2+kf)<<9)+ro];                 \
            short8 ah1 = *(const short8*)&Ahi[((1*2+kf)<<9)+ro];                 \
            short8 al0 = *(const short8*)&Alo[((0*2+kf)<<9)+ro];                 \
            short8 al1 = *(const short8*)&Alo[((1*2+kf)<<9)+ro];                 \
            short8 bgh = *(const short8*)&Bhi[(((w  )*2+kf)<<9)+ro];             \
            short8 bgl = *(const short8*)&Blo[(((w  )*2+kf)<<9)+ro];             \
            short8 buh = *(const short8*)&Bhi[(((4+w)*2+kf)<<9)+ro];             \
            short8 bul = *(const short8*)&Blo[(((4+w)*2+kf)<<9)+ro];             \
            accg[0] = MFMA(ah0,bgh,accg[0]);                                     \
            accg[1] = MFMA(ah1,bgh,accg[1]);                                     \
            accu[0] = MFMA(ah0,buh,accu[0]);                                     \
            accu[1] = MFMA(ah1,buh,accu[1]);                                     \
            accg[0] = MFMA(al0,bgh,accg[0]);                                     \
            accg[1] = MFMA(al1,bgh,accg[1]);                                     \
            accu[0] = MFMA(al0,buh,accu[0]);                                     \
            accu[1] = MFMA(al1,buh,accu[1]);                                     \
            accg[0] = MFMA(ah0,bgl,accg[0]);                                     \
            accg[1] = MFMA(ah1,bgl,accg[1]);                                     \
            accu[0] = MFMA(ah0,bul,accu[0]);                                     \
            accu[1] = MFMA(ah1,bul,accu[1]);                                     \
        }                                                                        \
    }

    for (int kst = 0; kst < 32; kst += 2) {
        S1_BODY(a0c,a1c,bvc,a0n,a1n,bvn,kst)
        S1_BODY(a0n,a1n,bvn,a0c,a1c,bvc,kst+1)
    }
#undef S1_BODY

    const int crhi = (lane>>5)*4, cl = lane&31;
    const int colg = n0 + 32*w + cl;
    #pragma unroll
    for (int mi=0;mi<2;++mi)
      #pragma unroll
      for (int r=0;r<16;++r) {
        int row = mi*32 + (r&3) + 8*(r>>2) + crhi;
        if (m0 + row < cnt) {
            size_t base = (size_t)s_tk[row]*(2*INTER);
            atomicAdd(&gu[base + colg],         accg[mi][r]);
            atomicAdd(&gu[base + INTER + colg], accu[mi][r]);
        }
      }
}

// fuse: h = silu(gate)*up, write bf16 hi/lo planes for stage2 A
__global__ __launch_bounds__(256)
void fuse_kernel(const float* __restrict__ gu, ushort* __restrict__ hhi,
                 ushort* __restrict__ hlo) {
    int id  = blockIdx.x*256 + threadIdx.x;      // T_TOK*TOPK*INTER/4 threads
    int row = id / (INTER/4);
    int c4  = (id % (INTER/4)) * 4;
    const float* gr = gu + (size_t)row*(2*INTER) + c4;
    float4 g = *(const float4*)gr;
    float4 u = *(const float4*)(gr + INTER);
    float hv[4];
    hv[0] = g.x/(1.f+__expf(-g.x))*u.x;
    hv[1] = g.y/(1.f+__expf(-g.y))*u.y;
    hv[2] = g.z/(1.f+__expf(-g.z))*u.z;
    hv[3] = g.w/(1.f+__expf(-g.w))*u.w;
    ushort4 hh, hl;
    {
        ushort h0 = bf16h(hv[0]); float f0 = __uint_as_float(((uint32_t)h0)<<16);
        ushort h1 = bf16h(hv[1]); float f1 = __uint_as_float(((uint32_t)h1)<<16);
        ushort h2 = bf16h(hv[2]); float f2 = __uint_as_float(((uint32_t)h2)<<16);
        ushort h3 = bf16h(hv[3]); float f3 = __uint_as_float(((uint32_t)h3)<<16);
        hh = make_ushort4(h0,h1,h2,h3);
        hl = make_ushort4(bf16h(hv[0]-f0), bf16h(hv[1]-f1), bf16h(hv[2]-f2), bf16h(hv[3]-f3));
    }
    *(ushort4*)&hhi[(size_t)row*INTER + c4] = hh;
    *(ushort4*)&hlo[(size_t)row*INTER + c4] = hl;
}

// stage2: out[t] += w*(h . down^T). BM=64, BN=256, BK=32, K-split=2. 4 waves, wave = 64x64.
__global__ __launch_bounds__(256)
void stage2_kernel(const ushort* __restrict__ hhi, const ushort* __restrict__ hlo,
                   const float* __restrict__ dwn, const int* __restrict__ counts,
                   const int* __restrict__ pair_tk, const float* __restrict__ pair_w,
                   float* __restrict__ out) {
    __shared__ ushort Ahi[4*512], Alo[4*512];
    __shared__ ushort Bhi[16*512], Blo[16*512];
    __shared__ int   s_tk[64];
    __shared__ float s_w[64];

    const int e  = blockIdx.z >> 1;
    const int ks = blockIdx.z & 1;
    const int cnt = min(counts[e], CAP);
    const int m0  = blockIdx.y * 64;
    if (m0 >= cnt) return;
    const int n0  = blockIdx.x * 256;

    const int tid = threadIdx.x, lane = tid & 63, w = tid >> 6;
    if (tid < 64) {
        int slot = min(m0+tid, cnt-1);
        s_tk[tid] = pair_tk[e*CAP + slot];
        s_w[tid]  = pair_w [e*CAP + slot];
    }
    __syncthreads();

    // A-stage role: run f = tid>>6 (0..3), ln = tid&63 (bf16 planes, no conversion)
    const int fA = tid >> 6, lnA = tid & 63;
    const int arow = (fA>>1)*32 + (lnA & 31);
    const int aoct = lnA >> 5, akf = fA & 1;
    const size_t aoff = (size_t)s_tk[arow]*INTER + ks*384 + akf*16 + aoct*8;
    const ushort* ahsrc = hhi + aoff;
    const ushort* alsrc = hlo + aoff;

    const int br = tid;
    const float* bsrc = dwn + (size_t)e*HID*INTER + (size_t)(n0+br)*INTER + ks*384;
    const int rgB = br >> 5, lnB = br & 31;

    f32x16 acc[2][2];
    #pragma unroll
    for (int mi=0;mi<2;++mi)
      #pragma unroll
      for (int ni=0;ni<2;++ni)
        #pragma unroll
        for (int i=0;i<16;++i) acc[mi][ni][i] = 0.f;

    short8 ahc, alc, ahn, aln;
    float4 bvc[8], bvn[8];
    ahc = *(const short8*)(ahsrc);
    alc = *(const short8*)(alsrc);
    #pragma unroll
    for (int q=0;q<8;++q) bvc[q] = *(const float4*)(bsrc + 4*q);

#define S2_BODY(AH,AL,BV,AHN,ALN,BVN,KST)                                        \
    {                                                                            \
        __syncthreads();                                                         \
        *(short8*)&Ahi[(fA<<9)+(lnA<<3)] = AH;                                   \
        *(short8*)&Alo[(fA<<9)+(lnA<<3)] = AL;                                   \
        _Pragma("unroll")                                                        \
        for (int o=0;o<4;++o) { short8 h,l; split8(BV[2*o],BV[2*o+1],h,l);       \
          int f = rgB*2 + (o>>1); int ln = lnB + 32*(o&1);                       \
          *(short8*)&Bhi[(f<<9)+(ln<<3)] = h;                                    \
          *(short8*)&Blo[(f<<9)+(ln<<3)] = l; }                                  \
        if ((KST)+1 < 12) {                                                      \
            int ko = ((KST)+1)*32;                                               \
            AHN = *(const short8*)(ahsrc + ko);                                  \
            ALN = *(const short8*)(alsrc + ko);                                  \
            _Pragma("unroll")                                                    \
            for (int q=0;q<8;++q) BVN[q] = *(const float4*)(bsrc + ko + 4*q);    \
        }                                                                        \
        __syncthreads();                                                         \
        const int ro = lane << 3;                                                \
        _Pragma("unroll")                                                        \
        for (int kf=0;kf<2;++kf) {                                               \
            short8 ah0 = *(const short8*)&Ahi[((0*2+kf)<<9)+ro];                 \
            short8 ah1 = *(const short8*)&Ahi[((1*2+kf)<<9)+ro];                 \
            short8 al0 = *(const short8*)&Alo[((0*2+kf)<<9)+ro];                 \
            short8 al1 = *(const short8*)&Alo[((1*2+kf)<<9)+ro];                 \
            _Pragma("unroll")                                                    \
            for (int ni=0;ni<2;++ni) {                                           \
                short8 bh = *(const short8*)&Bhi[(((2*w+ni)*2+kf)<<9)+ro];       \
                short8 bl = *(const short8*)&Blo[(((2*w+ni)*2+kf)<<9)+ro];       \
                acc[0][ni] = MFMA(ah0,bh,acc[0][ni]);                            \
                acc[1][ni] = MFMA(ah1,bh,acc[1][ni]);                            \
                acc[0][ni] = MFMA(al0,bh,acc[0][ni]);                            \
                acc[1][ni] = MFMA(al1,bh,acc[1][ni]);                            \
                acc[0][ni] = MFMA(ah0,bl,acc[0][ni]);                            \
                acc[1][ni] = MFMA(ah1,bl,acc[1][ni]);                            \
            }                                                                    \
        }                                                                        \
    }

    for (int kst = 0; kst < 12; kst += 2) {
        S2_BODY(ahc,alc,bvc,ahn,aln,bvn,kst)
        S2_BODY(ahn,aln,bvn,ahc,alc,bvc,kst+1)
    }
#undef S2_BODY

    const int crhi = (lane>>5)*4, cl = lane&31;
    #pragma unroll
    for (int mi=0;mi<2;++mi)
      #pragma unroll
      for (int r=0;r<16;++r) {
        int row = mi*32 + (r&3) + 8*(r>>2) + crhi;
        if (m0 + row < cnt) {
            int   t  = s_tk[row] >> 1;     // TOPK == 2
            float wt = s_w[row];
            #pragma unroll
            for (int ni=0;ni<2;++ni) {
                int col = n0 + 64*w + 32*ni + cl;
                atomicAdd(&out[(size_t)t*HID + col], wt*acc[mi][ni][r]);
            }
        }
      }
}

extern "C" void kernel_launch(void* const* d_in, const int* in_sizes, int n_in,
                              void* d_out, int out_size, void* d_ws, size_t ws_size,
                              hipStream_t stream) {
    const float* hs  = (const float*)d_in[0];
    const int*   idx = (const int*)  d_in[1];
    const float* wts = (const float*)d_in[2];
    const float* gup = (const float*)d_in[3];
    const float* dwn = (const float*)d_in[4];
    float* out = (float*)d_out;

    char* ws = (char*)d_ws;
    int*    counts  = (int*)ws;
    int*    pair_tk = (int*)(ws + 1024);
    float*  pair_w  = (float*)(ws + 1024 + NEXP*CAP*4);
    float*  gu      = (float*)(ws + 262144);
    ushort* hhi     = (ushort*)(ws + 262144 + 25165824);
    ushort* hlo     = (ushort*)(ws + 262144 + 25165824 + 6291456);

    hipMemsetAsync(counts, 0, NEXP*sizeof(int), stream);
    hipMemsetAsync(gu, 0, (size_t)T_TOK*TOPK*2*INTER*sizeof(float), stream);
    hipMemsetAsync(out, 0, (size_t)T_TOK*HID*sizeof(float), stream);

    route_kernel<<<(T_TOK*TOPK + 255)/256, 256, 0, stream>>>(idx, wts, counts, pair_tk, pair_w);
    stage1_kernel<<<dim3(INTER/128, MBLK, NEXP*2), 256, 0, stream>>>(hs, gup, counts, pair_tk, gu);
    fuse_kernel<<<(T_TOK*TOPK*INTER/4)/256, 256, 0, stream>>>(gu, hhi, hlo);
    stage2_kernel<<<dim3(HID/256, MBLK, NEXP*2), 256, 0, stream>>>(hhi, hlo, dwn, counts, pair_tk, pair_w, out);
}

// Round 6
// 634.309 us; speedup vs baseline: 1.8613x; 1.0069x over previous
//
#include <hip/hip_runtime.h>
#include <hip/hip_bf16.h>
#include <cstdint>
#include <cstddef>

#define T_TOK 2048
#define HID   2048
#define NEXP  16
#define INTER 768
#define TOPK  2
#define CAP   1024
#define MBLK  8

using short8  = __attribute__((ext_vector_type(8))) short;
using f32x16  = __attribute__((ext_vector_type(16))) float;

#define MFMA(a,b,c) __builtin_amdgcn_mfma_f32_32x32x16_bf16((a),(b),(c),0,0,0)

__device__ inline ushort bf16h(float x) {
    union { __hip_bfloat16 b; ushort u; } cv; cv.b = __float2bfloat16(x); return cv.u;
}
__device__ inline void gl16(const void* g, void* l) {
    __builtin_amdgcn_global_load_lds((const __attribute__((address_space(1))) void*)g,
                                     (__attribute__((address_space(3))) void*)l, 16, 0, 0);
}
__device__ inline void split8(float4 a, float4 b, short8& h, short8& l) {
    float v[8] = {a.x,a.y,a.z,a.w,b.x,b.y,b.z,b.w};
    #pragma unroll
    for (int j = 0; j < 8; ++j) {
        ushort hb = bf16h(v[j]);
        float hf = __uint_as_float(((uint32_t)hb) << 16);
        h[j] = (short)hb;
        l[j] = (short)bf16h(v[j] - hf);
    }
}

__global__ __launch_bounds__(256)
void route_kernel(const int* __restrict__ idx, const float* __restrict__ wts,
                  int* __restrict__ counts, int* __restrict__ pair_tk,
                  float* __restrict__ pair_w) {
    int p = blockIdx.x * blockDim.x + threadIdx.x;
    if (p >= T_TOK * TOPK) return;
    int e = idx[p];
    int pos = atomicAdd(&counts[e], 1);
    if (pos < CAP) {
        pair_tk[e * CAP + pos] = p;
        pair_w [e * CAP + pos] = wts[p];
    }
}

__global__ __launch_bounds__(256)
void prep_bf16_kernel(const float4* __restrict__ src, ushort4* __restrict__ dst, int n4) {
    int stride = gridDim.x * blockDim.x;
    for (int i = blockIdx.x*blockDim.x + threadIdx.x; i < n4; i += stride) {
        float4 v = src[i];
        dst[i] = make_ushort4(bf16h(v.x), bf16h(v.y), bf16h(v.z), bf16h(v.w));
    }
}

__global__ __launch_bounds__(256)
void prep_hilo_kernel(const float4* __restrict__ src, ushort4* __restrict__ hi,
                      ushort4* __restrict__ lo, int n4) {
    int stride = gridDim.x * blockDim.x;
    for (int i = blockIdx.x*blockDim.x + threadIdx.x; i < n4; i += stride) {
        float4 v = src[i];
        ushort h0=bf16h(v.x), h1=bf16h(v.y), h2=bf16h(v.z), h3=bf16h(v.w);
        hi[i] = make_ushort4(h0,h1,h2,h3);
        lo[i] = make_ushort4(bf16h(v.x - __uint_as_float((uint32_t)h0<<16)),
                             bf16h(v.y - __uint_as_float((uint32_t)h1<<16)),
                             bf16h(v.z - __uint_as_float((uint32_t)h2<<16)),
                             bf16h(v.w - __uint_as_float((uint32_t)h3<<16)));
    }
}

// ---------------- fast path: global_load_lds staged, bf16-B 2-term ----------------
// stage1: BM=64, BNpair=128, BK=32, K-split=2. gu += (hs_hi+hs_lo) . gupb^T
__global__ __launch_bounds__(256, 3)
void s1mm_kernel(const ushort* __restrict__ hshi, const ushort* __restrict__ hslo,
                 const ushort* __restrict__ gupb,
                 const int* __restrict__ counts, const int* __restrict__ pair_tk,
                 float* __restrict__ gu) {
    __shared__ ushort Ab[2][8*512];    // frag f=(plane*2+rgA)*2+kf
    __shared__ ushort Bb[2][16*512];   // frag f=rg*2+kf (rg0-3 gate, 4-7 up)
    __shared__ int s_tk[64];

    const int lin  = blockIdx.x;                      // 1536 = 8*192
    const int work = (lin & 7)*192 + (lin >> 3);      // XCD-sibling grouping
    const int x = work % 6, y = (work/6) & 7, z = work/48;
    const int e = z >> 1, ks = z & 1;
    const int cnt = min(counts[e], CAP);
    const int m0 = y*64;
    if (m0 >= cnt) return;
    const int n0 = x*128;

    const int tid = threadIdx.x, ln = tid & 63, w = tid >> 6;
    if (tid < 64) s_tk[tid] = pair_tk[e*CAP + min(m0+tid, cnt-1)];
    __syncthreads();

    const int lr = ln & 31, oc = (ln >> 5)*8;
    const int tkA = s_tk[(w & 1)*32 + lr];
    const ushort* hp = (w >> 1) ? hslo : hshi;
    const ushort* aA = hp + (size_t)(tkA >> 1)*HID + ks*1024 + oc;
    const ushort* bG = gupb + ((size_t)e*(2*INTER) + (n0 + w*32 + lr))*HID + ks*1024 + oc;
    const ushort* bU = gupb + ((size_t)e*(2*INTER) + (INTER + n0 + w*32 + lr))*HID + ks*1024 + oc;

    f32x16 accg[2], accu[2];
    #pragma unroll
    for (int i=0;i<16;++i){accg[0][i]=0.f;accg[1][i]=0.f;accu[0][i]=0.f;accu[1][i]=0.f;}

#define S1_STAGE(buf, k32) { const int kb=(k32)*32;            \
    gl16(aA+kb,    &Ab[buf][(2*w+0)*512]);                     \
    gl16(aA+kb+16, &Ab[buf][(2*w+1)*512]);                     \
    gl16(bG+kb,    &Bb[buf][(2*w+0)*512]);                     \
    gl16(bG+kb+16, &Bb[buf][(2*w+1)*512]);                     \
    gl16(bU+kb,    &Bb[buf][(2*(4+w)+0)*512]);                 \
    gl16(bU+kb+16, &Bb[buf][(2*(4+w)+1)*512]); }

    S1_STAGE(0, 0)
    int cur = 0;
    const int ro = ln*8;
    for (int k32 = 0; k32 < 32; ++k32) {
        __syncthreads();                    // drains vmcnt: buf[cur] ready, prev reads done
        if (k32 + 1 < 32) S1_STAGE(cur^1, k32+1)
        #pragma unroll
        for (int kf = 0; kf < 2; ++kf) {
            short8 ah0 = *(const short8*)&Ab[cur][(0+kf)*512 + ro];
            short8 ah1 = *(const short8*)&Ab[cur][(2+kf)*512 + ro];
            short8 al0 = *(const short8*)&Ab[cur][(4+kf)*512 + ro];
            short8 al1 = *(const short8*)&Ab[cur][(6+kf)*512 + ro];
            short8 bg  = *(const short8*)&Bb[cur][(2*w+kf)*512 + ro];
            short8 bu  = *(const short8*)&Bb[cur][(8+2*w+kf)*512 + ro];
            accg[0]=MFMA(ah0,bg,accg[0]); accg[0]=MFMA(al0,bg,accg[0]);
            accg[1]=MFMA(ah1,bg,accg[1]); accg[1]=MFMA(al1,bg,accg[1]);
            accu[0]=MFMA(ah0,bu,accu[0]); accu[0]=MFMA(al0,bu,accu[0]);
            accu[1]=MFMA(ah1,bu,accu[1]); accu[1]=MFMA(al1,bu,accu[1]);
        }
        cur ^= 1;
    }
#undef S1_STAGE

    const int crhi = (ln>>5)*4, cl = ln&31;
    const int colg = n0 + 32*w + cl;
    #pragma unroll
    for (int mi=0;mi<2;++mi)
      #pragma unroll
      for (int r=0;r<16;++r) {
        int row = mi*32 + (r&3) + 8*(r>>2) + crhi;
        if (m0 + row < cnt) {
            size_t base = (size_t)s_tk[row]*(2*INTER);
            atomicAdd(&gu[base + colg],         accg[mi][r]);
            atomicAdd(&gu[base + INTER + colg], accu[mi][r]);
        }
      }
}

// fuse: h = silu(gate)*up -> bf16 hi/lo planes
__global__ __launch_bounds__(256)
void fuse_kernel(const float* __restrict__ gu, ushort* __restrict__ hhi,
                 ushort* __restrict__ hlo) {
    int id  = blockIdx.x*256 + threadIdx.x;
    int row = id / (INTER/4);
    int c4  = (id % (INTER/4)) * 4;
    const float* gr = gu + (size_t)row*(2*INTER) + c4;
    float4 g = *(const float4*)gr;
    float4 u = *(const float4*)(gr + INTER);
    float hv[4];
    hv[0] = g.x/(1.f+__expf(-g.x))*u.x;
    hv[1] = g.y/(1.f+__expf(-g.y))*u.y;
    hv[2] = g.z/(1.f+__expf(-g.z))*u.z;
    hv[3] = g.w/(1.f+__expf(-g.w))*u.w;
    ushort h0=bf16h(hv[0]), h1=bf16h(hv[1]), h2=bf16h(hv[2]), h3=bf16h(hv[3]);
    *(ushort4*)&hhi[(size_t)row*INTER + c4] = make_ushort4(h0,h1,h2,h3);
    *(ushort4*)&hlo[(size_t)row*INTER + c4] = make_ushort4(
        bf16h(hv[0]-__uint_as_float((uint32_t)h0<<16)),
        bf16h(hv[1]-__uint_as_float((uint32_t)h1<<16)),
        bf16h(hv[2]-__uint_as_float((uint32_t)h2<<16)),
        bf16h(hv[3]-__uint_as_float((uint32_t)h3<<16)));
}

// stage2: BM=64, BN=256, BK=32, K-split=2. out += w*((h_hi+h_lo) . dwnb^T)
__global__ __launch_bounds__(256, 3)
void s2mm_kernel(const ushort* __restrict__ h2hi, const ushort* __restrict__ h2lo,
                 const ushort* __restrict__ dwnb,
                 const int* __restrict__ counts, const int* __restrict__ pair_tk,
                 const float* __restrict__ pair_w, float* __restrict__ out) {
    __shared__ ushort Ab[2][8*512];
    __shared__ ushort Bb[2][16*512];   // frag f=rg*2+kf, rg=0..7 (wave w: 2w,2w+1)
    __shared__ int   s_tk[64];
    __shared__ float s_w[64];

    const int lin  = blockIdx.x;                      // 2048 = 8*256
    const int work = (lin & 7)*256 + (lin >> 3);
    const int x = work & 7, y = (work >> 3) & 7, z = work >> 6;
    const int e = z >> 1, ks = z & 1;
    const int cnt = min(counts[e], CAP);
    const int m0 = y*64;
    if (m0 >= cnt) return;
    const int n0 = x*256;

    const int tid = threadIdx.x, ln = tid & 63, w = tid >> 6;
    if (tid < 64) {
        int s = min(m0+tid, cnt-1);
        s_tk[tid] = pair_tk[e*CAP + s];
        s_w[tid]  = pair_w [e*CAP + s];
    }
    __syncthreads();

    const int lr = ln & 31, oc = (ln >> 5)*8;
    const int tkA = s_tk[(w & 1)*32 + lr];
    const ushort* hp = (w >> 1) ? h2lo : h2hi;
    const ushort* aA = hp + (size_t)tkA*INTER + ks*384 + oc;
    const ushort* b0 = dwnb + ((size_t)e*HID + (n0 + (2*w+0)*32 + lr))*INTER + ks*384 + oc;
    const ushort* b1 = dwnb + ((size_t)e*HID + (n0 + (2*w+1)*32 + lr))*INTER + ks*384 + oc;

    f32x16 acc[2][2];
    #pragma unroll
    for (int mi=0;mi<2;++mi)
      #pragma unroll
      for (int ni=0;ni<2;++ni)
        #pragma unroll
        for (int i=0;i<16;++i) acc[mi][ni][i] = 0.f;

#define S2_STAGE(buf, k32) { const int kb=(k32)*32;            \
    gl16(aA+kb,    &Ab[buf][(2*w+0)*512]);                     \
    gl16(aA+kb+16, &Ab[buf][(2*w+1)*512]);                     \
    gl16(b0+kb,    &Bb[buf][(4*w+0)*512]);                     \
    gl16(b0+kb+16, &Bb[buf][(4*w+1)*512]);                     \
    gl16(b1+kb,    &Bb[buf][(4*w+2)*512]);                     \
    gl16(b1+kb+16, &Bb[buf][(4*w+3)*512]); }

    S2_STAGE(0, 0)
    int cur = 0;
    const int ro = ln*8;
    for (int k32 = 0; k32 < 12; ++k32) {
        __syncthreads();
        if (k32 + 1 < 12) S2_STAGE(cur^1, k32+1)
        #pragma unroll
        for (int kf = 0; kf < 2; ++kf) {
            short8 ah0 = *(const short8*)&Ab[cur][(0+kf)*512 + ro];
            short8 ah1 = *(const short8*)&Ab[cur][(2+kf)*512 + ro];
            short8 al0 = *(const short8*)&Ab[cur][(4+kf)*512 + ro];
            short8 al1 = *(const short8*)&Ab[cur][(6+kf)*512 + ro];
            short8 b0f = *(const short8*)&Bb[cur][(4*w+0+kf)*512 + ro];
            short8 b1f = *(const short8*)&Bb[cur][(4*w+2+kf)*512 + ro];
            acc[0][0]=MFMA(ah0,b0f,acc[0][0]); acc[0][0]=MFMA(al0,b0f,acc[0][0]);
            acc[1][0]=MFMA(ah1,b0f,acc[1][0]); acc[1][0]=MFMA(al1,b0f,acc[1][0]);
            acc[0][1]=MFMA(ah0,b1f,acc[0][1]); acc[0][1]=MFMA(al0,b1f,acc[0][1]);
            acc[1][1]=MFMA(ah1,b1f,acc[1][1]); acc[1][1]=MFMA(al1,b1f,acc[1][1]);
        }
        cur ^= 1;
    }
#undef S2_STAGE

    const int crhi = (ln>>5)*4, cl = ln&31;
    #pragma unroll
    for (int mi=0;mi<2;++mi)
      #pragma unroll
      for (int r=0;r<16;++r) {
        int row = mi*32 + (r&3) + 8*(r>>2) + crhi;
        if (m0 + row < cnt) {
            int   t  = s_tk[row] >> 1;     // TOPK == 2
            float wt = s_w[row];
            #pragma unroll
            for (int ni=0;ni<2;++ni) {
                int col = n0 + 64*w + 32*ni + cl;
                atomicAdd(&out[(size_t)t*HID + col], wt*acc[mi][ni][r]);
            }
        }
      }
}

// ---------------- fallback path (round-4, measured-correct; used if ws too small) ----
__global__ __launch_bounds__(256)
void s1_fb_kernel(const float* __restrict__ hs, const float* __restrict__ gup,
                  const int* __restrict__ counts, const int* __restrict__ pair_tk,
                  float* __restrict__ gu) {
    __shared__ ushort Ahi[4*512], Alo[4*512];
    __shared__ ushort Bhi[16*512], Blo[16*512];
    __shared__ int s_tk[64];
    const int e  = blockIdx.z >> 1;
    const int ks = blockIdx.z & 1;
    const int cnt = min(counts[e], CAP);
    const int m0  = blockIdx.y * 64;
    if (m0 >= cnt) return;
    const int n0  = blockIdx.x * 128;
    const int tid = threadIdx.x, lane = tid & 63, w = tid >> 6;
    if (tid < 64) s_tk[tid] = pair_tk[e*CAP + min(m0+tid, cnt-1)];
    __syncthreads();
    const int ar = tid & 63, aq = tid >> 6;
    const float* asrc = hs + (size_t)(s_tk[ar] >> 1)*HID + ks*1024 + aq*8;
    const int br = tid;
    const float* bsrc = gup + (size_t)e*(2*INTER)*HID
                      + (size_t)((br < 128) ? (n0+br) : (INTER + n0 + br - 128))*HID + ks*1024;
    const int fA  = (ar>>5)*2 + (aq>>1);
    const int lnA = (ar&31) + 32*(aq&1);
    const int rgB = br >> 5, lnB = br & 31;
    f32x16 accg[2], accu[2];
    #pragma unroll
    for (int i=0;i<16;++i){ accg[0][i]=0.f; accg[1][i]=0.f; accu[0][i]=0.f; accu[1][i]=0.f; }
    float4 a0c,a1c,bvc[8], a0n,a1n,bvn[8];
    a0c = *(const float4*)(asrc + 0);
    a1c = *(const float4*)(asrc + 4);
    #pragma unroll
    for (int q=0;q<8;++q) bvc[q] = *(const float4*)(bsrc + 4*q);
#define S1_BODY(A0,A1,BV,A0N,A1N,BVN,KST)                                        \
    {                                                                            \
        __syncthreads();                                                         \
        { short8 h,l; split8(A0,A1,h,l);                                         \
          *(short8*)&Ahi[(fA<<9)+(lnA<<3)] = h;                                  \
          *(short8*)&Alo[(fA<<9)+(lnA<<3)] = l; }                                \
        _Pragma("unroll")                                                        \
        for (int o=0;o<4;++o) { short8 h,l; split8(BV[2*o],BV[2*o+1],h,l);       \
          int f = rgB*2 + (o>>1); int ln2 = lnB + 32*(o&1);                      \
          *(short8*)&Bhi[(f<<9)+(ln2<<3)] = h;                                   \
          *(short8*)&Blo[(f<<9)+(ln2<<3)] = l; }                                 \
        if ((KST)+1 < 32) {                                                     \
            int ko = ((KST)+1)*32;                                              \
            A0N = *(const float4*)(asrc + ko);                                  \
            A1N = *(const float4*)(asrc + ko + 4);                              \
            _Pragma("unroll")                                                   \
            for (int q=0;q<8;++q) BVN[q] = *(const float4*)(bsrc + ko + 4*q);   \
        }                                                                       \
        __syncthreads();                                                        \
        const int ro = lane << 3;                                               \
        _Pragma("unroll")                                                       \
        for (int kf=0;kf<2;++kf) {                                              \
            short8 ah0 = *(const short8*)&Ahi[((0*2+kf)<<9)+ro];                \
            short8 ah1 = *(const short8*)&Ahi[((1*2+kf)<<9)+ro];                \
            short8 al0 = *(const short8*)&Alo[((0*2+kf)<<9)+ro];                \
            short8 al1 = *(const short8*)&Alo[((1*2+kf)<<9)+ro];                \
            short8 bgh = *(const short8*)&Bhi[(((w  )*2+kf)<<9)+ro];            \
            short8 bgl = *(const short8*)&Blo[(((w  )*2+kf)<<9)+ro];            \
            short8 buh = *(const short8*)&Bhi[(((4+w)*2+kf)<<9)+ro];            \
            short8 bul = *(const short8*)&Blo[(((4+w)*2+kf)<<9)+ro];            \
            accg[0] = MFMA(ah0,bgh,accg[0]);                                    \
            accg[1] = MFMA(ah1,bgh,accg[1]);                                    \
            accu[0] = MFMA(ah0,buh,accu[0]);                                    \
            accu[1] = MFMA(ah1,buh,accu[1]);                                    \
            accg[0] = MFMA(al0,bgh,accg[0]);                                    \
            accg[1] = MFMA(al1,bgh,accg[1]);                                    \
            accu[0] = MFMA(al0,buh,accu[0]);                                    \
            accu[1] = MFMA(al1,buh,accu[1]);                                    \
            accg[0] = MFMA(ah0,bgl,accg[0]);                                    \
            accg[1] = MFMA(ah1,bgl,accg[1]);                                    \
            accu[0] = MFMA(ah0,bul,accu[0]);                                    \
            accu[1] = MFMA(ah1,bul,accu[1]);                                    \
        }                                                                       \
    }
    for (int kst = 0; kst < 32; kst += 2) {
        S1_BODY(a0c,a1c,bvc,a0n,a1n,bvn,kst)
        S1_BODY(a0n,a1n,bvn,a0c,a1c,bvc,kst+1)
    }
#undef S1_BODY
    const int crhi = (lane>>5)*4, cl = lane&31;
    const int colg = n0 + 32*w + cl;
    #pragma unroll
    for (int mi=0;mi<2;++mi)
      #pragma unroll
      for (int r=0;r<16;++r) {
        int row = mi*32 + (r&3) + 8*(r>>2) + crhi;
        if (m0 + row < cnt) {
            size_t base = (size_t)s_tk[row]*(2*INTER);
            atomicAdd(&gu[base + colg],         accg[mi][r]);
            atomicAdd(&gu[base + INTER + colg], accu[mi][r]);
        }
      }
}

__global__ __launch_bounds__(256)
void s2_fb_kernel(const ushort* __restrict__ hhi, const ushort* __restrict__ hlo,
                  const float* __restrict__ dwn, const int* __restrict__ counts,
                  const int* __restrict__ pair_tk, const float* __restrict__ pair_w,
                  float* __restrict__ out) {
    __shared__ ushort Ahi[4*512], Alo[4*512];
    __shared__ ushort Bhi[16*512], Blo[16*512];
    __shared__ int   s_tk[64];
    __shared__ float s_w[64];
    const int e  = blockIdx.z >> 1;
    const int ks = blockIdx.z & 1;
    const int cnt = min(counts[e], CAP);
    const int m0  = blockIdx.y * 64;
    if (m0 >= cnt) return;
    const int n0  = blockIdx.x * 256;
    const int tid = threadIdx.x, lane = tid & 63, w = tid >> 6;
    if (tid < 64) {
        int slot = min(m0+tid, cnt-1);
        s_tk[tid] = pair_tk[e*CAP + slot];
        s_w[tid]  = pair_w [e*CAP + slot];
    }
    __syncthreads();
    const int fA = tid >> 6, lnA = tid & 63;
    const int arow = (fA>>1)*32 + (lnA & 31);
    const int aoct = lnA >> 5, akf = fA & 1;
    const size_t aoff = (size_t)s_tk[arow]*INTER + ks*384 + akf*16 + aoct*8;
    const ushort* ahsrc = hhi + aoff;
    const ushort* alsrc = hlo + aoff;
    const int br = tid;
    const float* bsrc = dwn + (size_t)e*HID*INTER + (size_t)(n0+br)*INTER + ks*384;
    const int rgB = br >> 5, lnB = br & 31;
    f32x16 acc[2][2];
    #pragma unroll
    for (int mi=0;mi<2;++mi)
      #pragma unroll
      for (int ni=0;ni<2;++ni)
        #pragma unroll
        for (int i=0;i<16;++i) acc[mi][ni][i] = 0.f;
    short8 ahc, alc, ahn, aln;
    float4 bvc[8], bvn[8];
    ahc = *(const short8*)(ahsrc);
    alc = *(const short8*)(alsrc);
    #pragma unroll
    for (int q=0;q<8;++q) bvc[q] = *(const float4*)(bsrc + 4*q);
#define S2_BODY(AH,AL,BV,AHN,ALN,BVN,KST)                                        \
    {                                                                            \
        __syncthreads();                                                         \
        *(short8*)&Ahi[(fA<<9)+(lnA<<3)] = AH;                                   \
        *(short8*)&Alo[(fA<<9)+(lnA<<3)] = AL;                                   \
        _Pragma("unroll")                                                        \
        for (int o=0;o<4;++o) { short8 h,l; split8(BV[2*o],BV[2*o+1],h,l);       \
          int f = rgB*2 + (o>>1); int ln2 = lnB + 32*(o&1);                      \
          *(short8*)&Bhi[(f<<9)+(ln2<<3)] = h;                                   \
          *(short8*)&Blo[(f<<9)+(ln2<<3)] = l; }                                 \
        if ((KST)+1 < 12) {                                                     \
            int ko = ((KST)+1)*32;                                              \
            AHN = *(const short8*)(ahsrc + ko);                                 \
            ALN = *(const short8*)(alsrc + ko);                                 \
            _Pragma("unroll")                                                   \
            for (int q=0;q<8;++q) BVN[q] = *(const float4*)(bsrc + ko + 4*q);   \
        }                                                                       \
        __syncthreads();                                                        \
        const int ro = lane << 3;                                               \
        _Pragma("unroll")                                                       \
        for (int kf=0;kf<2;++kf) {                                              \
            short8 ah0 = *(const short8*)&Ahi[((0*2+kf)<<9)+ro];                \
            short8 ah1 = *(const short8*)&Ahi[((1*2+kf)<<9)+ro];                \
            short8 al0 = *(const short8*)&Alo[((0*2+kf)<<9)+ro];                \
            short8 al1 = *(const short8*)&Alo[((1*2+kf)<<9)+ro];                \
            _Pragma("unroll")                                                   \
            for (int ni=0;ni<2;++ni) {                                          \
                short8 bh = *(const short8*)&Bhi[(((2*w+ni)*2+kf)<<9)+ro];      \
                short8 bl = *(const short8*)&Blo[(((2*w+ni)*2+kf)<<9)+ro];      \
                acc[0][ni] = MFMA(ah0,bh,acc[0][ni]);                           \
                acc[1][ni] = MFMA(ah1,bh,acc[1][ni]);                           \
                acc[0][ni] = MFMA(al0,bh,acc[0][ni]);                           \
                acc[1][ni] = MFMA(al1,bh,acc[1][ni]);                           \
                acc[0][ni] = MFMA(ah0,bl,acc[0][ni]);                           \
                acc[1][ni] = MFMA(ah1,bl,acc[1][ni]);                           \
            }                                                                   \
        }                                                                       \
    }
    for (int kst = 0; kst < 12; kst += 2) {
        S2_BODY(ahc,alc,bvc,ahn,aln,bvn,kst)
        S2_BODY(ahn,aln,bvn,ahc,alc,bvc,kst+1)
    }
#undef S2_BODY
    const int crhi = (lane>>5)*4, cl = lane&31;
    #pragma unroll
    for (int mi=0;mi<2;++mi)
      #pragma unroll
      for (int r=0;r<16;++r) {
        int row = mi*32 + (r&3) + 8*(r>>2) + crhi;
        if (m0 + row < cnt) {
            int   t  = s_tk[row] >> 1;
            float wt = s_w[row];
            #pragma unroll
            for (int ni=0;ni<2;++ni) {
                int col = n0 + 64*w + 32*ni + cl;
                atomicAdd(&out[(size_t)t*HID + col], wt*acc[mi][ni][r]);
            }
        }
      }
}

extern "C" void kernel_launch(void* const* d_in, const int* in_sizes, int n_in,
                              void* d_out, int out_size, void* d_ws, size_t ws_size,
                              hipStream_t stream) {
    const float* hs  = (const float*)d_in[0];
    const int*   idx = (const int*)  d_in[1];
    const float* wts = (const float*)d_in[2];
    const float* gup = (const float*)d_in[3];
    const float* dwn = (const float*)d_in[4];
    float* out = (float*)d_out;

    char* ws = (char*)d_ws;
    int*   counts  = (int*)ws;
    int*   pair_tk = (int*)(ws + 1024);
    float* pair_w  = (float*)(ws + 1024 + NEXP*CAP*4);

    // fast-path layout
    size_t o_gu   = 262144;
    size_t o_gupb = o_gu   + (size_t)T_TOK*TOPK*2*INTER*4;      // 25165824
    size_t o_dwnb = o_gupb + (size_t)NEXP*2*INTER*HID*2;        // +100663296
    size_t o_hshi = o_dwnb + (size_t)NEXP*HID*INTER*2;          // +50331648
    size_t o_hslo = o_hshi + (size_t)T_TOK*HID*2;               // +8388608
    size_t o_h2hi = o_hslo + (size_t)T_TOK*HID*2;               // +8388608
    size_t o_h2lo = o_h2hi + (size_t)T_TOK*TOPK*INTER*2;        // +6291456
    size_t need   = o_h2lo + (size_t)T_TOK*TOPK*INTER*2;        // ~196.2 MiB

    hipMemsetAsync(counts, 0, NEXP*sizeof(int), stream);
    hipMemsetAsync(out, 0, (size_t)T_TOK*HID*sizeof(float), stream);
    route_kernel<<<(T_TOK*TOPK + 255)/256, 256, 0, stream>>>(idx, wts, counts, pair_tk, pair_w);

    if (ws_size >= need) {
        float*  gu   = (float*)(ws + o_gu);
        ushort* gupb = (ushort*)(ws + o_gupb);
        ushort* dwnb = (ushort*)(ws + o_dwnb);
        ushort* hshi = (ushort*)(ws + o_hshi);
        ushort* hslo = (ushort*)(ws + o_hslo);
        ushort* h2hi = (ushort*)(ws + o_h2hi);
        ushort* h2lo = (ushort*)(ws + o_h2lo);

        hipMemsetAsync(gu, 0, (size_t)T_TOK*TOPK*2*INTER*4, stream);
        prep_bf16_kernel<<<2048, 256, 0, stream>>>((const float4*)gup, (ushort4*)gupb,
                                                   NEXP*2*INTER*HID/4);
        prep_bf16_kernel<<<2048, 256, 0, stream>>>((const float4*)dwn, (ushort4*)dwnb,
                                                   NEXP*HID*INTER/4);
        prep_hilo_kernel<<<1024, 256, 0, stream>>>((const float4*)hs, (ushort4*)hshi,
                                                   (ushort4*)hslo, T_TOK*HID/4);
        s1mm_kernel<<<6*MBLK*NEXP*2, 256, 0, stream>>>(hshi, hslo, gupb, counts, pair_tk, gu);
        fuse_kernel<<<(T_TOK*TOPK*INTER/4)/256, 256, 0, stream>>>(gu, h2hi, h2lo);
        s2mm_kernel<<<8*MBLK*NEXP*2, 256, 0, stream>>>(h2hi, h2lo, dwnb, counts, pair_tk,
                                                       pair_w, out);
    } else {
        // round-4 fallback layout (~38 MB)
        float*  gu  = (float*)(ws + 262144);
        ushort* hhi = (ushort*)(ws + 262144 + 25165824);
        ushort* hlo = (ushort*)(ws + 262144 + 25165824 + 6291456);
        hipMemsetAsync(gu, 0, (size_t)T_TOK*TOPK*2*INTER*4, stream);
        s1_fb_kernel<<<dim3(INTER/128, MBLK, NEXP*2), 256, 0, stream>>>(hs, gup, counts,
                                                                        pair_tk, gu);
        fuse_kernel<<<(T_TOK*TOPK*INTER/4)/256, 256, 0, stream>>>(gu, hhi, hlo);
        s2_fb_kernel<<<dim3(HID/256, MBLK, NEXP*2), 256, 0, stream>>>(hhi, hlo, dwn, counts,
                                                                      pair_tk, pair_w, out);
    }
}

// Round 9
// 576.224 us; speedup vs baseline: 2.0489x; 1.1008x over previous
//
#include <hip/hip_runtime.h>
#include <hip/hip_bf16.h>
#include <cstdint>
#include <cstddef>

#define T_TOK 2048
#define HID   2048
#define NEXP  16
#define INTER 768
#define TOPK  2
#define CAP   1024
#define MBLK  8
#define GU_PLANE 6291456   // T_TOK*TOPK*2*INTER floats per ks-plane

using short8  = __attribute__((ext_vector_type(8))) short;
using f32x16  = __attribute__((ext_vector_type(16))) float;

#define MFMA(a,b,c) __builtin_amdgcn_mfma_f32_32x32x16_bf16((a),(b),(c),0,0,0)

__device__ inline ushort bf16h(float x) {
    union { __hip_bfloat16 b; ushort u; } cv; cv.b = __float2bfloat16(x); return cv.u;
}
__device__ inline void gl16(const void* g, void* l) {
    __builtin_amdgcn_global_load_lds((const __attribute__((address_space(1))) void*)g,
                                     (__attribute__((address_space(3))) void*)l, 16, 0, 0);
}
__device__ inline void split8(float4 a, float4 b, short8& h, short8& l) {
    float v[8] = {a.x,a.y,a.z,a.w,b.x,b.y,b.z,b.w};
    #pragma unroll
    for (int j = 0; j < 8; ++j) {
        ushort hb = bf16h(v[j]);
        float hf = __uint_as_float(((uint32_t)hb) << 16);
        h[j] = (short)hb;
        l[j] = (short)bf16h(v[j] - hf);
    }
}
__device__ inline short8 cvt8(float4 a, float4 b) {
    short8 r;
    r[0]=(short)bf16h(a.x); r[1]=(short)bf16h(a.y); r[2]=(short)bf16h(a.z); r[3]=(short)bf16h(a.w);
    r[4]=(short)bf16h(b.x); r[5]=(short)bf16h(b.y); r[6]=(short)bf16h(b.z); r[7]=(short)bf16h(b.w);
    return r;
}

__global__ __launch_bounds__(256)
void route_kernel(const int* __restrict__ idx, const float* __restrict__ wts,
                  int* __restrict__ counts, int* __restrict__ pair_tk,
                  float* __restrict__ pair_w) {
    int p = blockIdx.x * blockDim.x + threadIdx.x;
    if (p >= T_TOK * TOPK) return;
    int e = idx[p];
    int pos = atomicAdd(&counts[e], 1);
    if (pos < CAP) {
        pair_tk[e * CAP + pos] = p;
        pair_w [e * CAP + pos] = wts[p];
    }
}

// -------- weight prep: write bf16 in fragment-major chunk order --------------
// B1 chunk (e, x 0..5, k32 0..63): ushort[16*512]; f = rg*2+kf;
//   rg<4: gate row = x*128+rg*32+(ln&31); rg>=4: up row = 768+x*128+(rg-4)*32+(ln&31)
//   k = k32*32 + kf*16 + (ln>>5)*8 + j
__global__ __launch_bounds__(256)
void prep_s1B_kernel(const float* __restrict__ gup, ushort* __restrict__ B1) {
    const int total = NEXP*6*64*1024;     // ushort8 slots
    int stride = gridDim.x * blockDim.x;
    for (int o = blockIdx.x*blockDim.x + threadIdx.x; o < total; o += stride) {
        int ln = o & 63, f = (o >> 6) & 15;
        int chunk = o >> 10;
        int k32 = chunk & 63, xe = chunk >> 6;
        int x = xe % 6, e = xe / 6;
        int rg = f >> 1, kf = f & 1;
        int grow = (rg < 4) ? (x*128 + rg*32 + (ln & 31))
                            : (768 + x*128 + (rg-4)*32 + (ln & 31));
        int gk = k32*32 + kf*16 + (ln >> 5)*8;
        const float* sp = gup + ((size_t)e*1536 + grow)*2048 + gk;
        float4 a = *(const float4*)sp;
        float4 b = *(const float4*)(sp + 4);
        *(short8*)(B1 + (size_t)o*8) = cvt8(a, b);
    }
}

// B2 chunk (e, x 0..7, k32 0..23): ushort[16*512]; f = rg*2+kf; rg 0..7
//   dwn row = x*256 + rg*32 + (ln&31);  k = k32*32 + kf*16 + (ln>>5)*8 + j
__global__ __launch_bounds__(256)
void prep_s2B_kernel(const float* __restrict__ dwn, ushort* __restrict__ B2) {
    const int total = NEXP*8*24*1024;
    int stride = gridDim.x * blockDim.x;
    for (int o = blockIdx.x*blockDim.x + threadIdx.x; o < total; o += stride) {
        int ln = o & 63, f = (o >> 6) & 15;
        int chunk = o >> 10;
        int k32 = chunk % 24, xe = chunk / 24;
        int x = xe & 7, e = xe >> 3;
        int rg = f >> 1, kf = f & 1;
        int grow = x*256 + rg*32 + (ln & 31);
        int gk = k32*32 + kf*16 + (ln >> 5)*8;
        const float* sp = dwn + ((size_t)e*2048 + grow)*768 + gk;
        float4 a = *(const float4*)sp;
        float4 b = *(const float4*)(sp + 4);
        *(short8*)(B2 + (size_t)o*8) = cvt8(a, b);
    }
}

// -------- stage1: BM=64 tokens, 128 gate+128 up cols, BK=32, K-split=2 -------
// B via coalesced gl16 chunks; A gathered in-kernel (fp32 read + split + ds_write),
// register-double-buffered so latency hides under MFMA. gu stores are plain (per-ks plane).
__global__ __launch_bounds__(256, 3)
void s1mm_kernel(const float* __restrict__ hs, const ushort* __restrict__ B1,
                 const int* __restrict__ counts, const int* __restrict__ pair_tk,
                 float* __restrict__ gu) {
    __shared__ ushort Ab[2][8*512];
    __shared__ ushort Bb[2][16*512];
    __shared__ int s_tk[64];

    const int lin  = blockIdx.x;                  // 1536 = 8*192
    const int work = (lin & 7)*192 + (lin >> 3);  // XCD grouping (bijective: 1536%8==0)
    const int x = work % 6, y = (work/6) & 7, z = work/48;
    const int e = z >> 1, ks = z & 1;
    const int cnt = min(counts[e], CAP);
    const int m0 = y*64;
    if (m0 >= cnt) return;

    const int tid = threadIdx.x, ln = tid & 63, w = tid >> 6;
    if (tid < 64) s_tk[tid] = pair_tk[e*CAP + min(m0+tid, cnt-1)];
    __syncthreads();

    // A staging role: slot s, k-quarter t4
    const int s = tid >> 2, t4 = tid & 3;
    const int rgA = s >> 5, kfA = t4 >> 1, ohA = t4 & 1;
    const int lnA = (s & 31) + 32*ohA;
    const int fH = rgA*2 + kfA;       // hi plane frag (p=0)
    const int fL = 4 + rgA*2 + kfA;   // lo plane frag (p=1)
    const float* asrc = hs + (size_t)(s_tk[s] >> 1)*HID + ks*1024 + t4*8;

    const ushort* B1e = B1 + (size_t)(e*6 + x)*64*8192;

    f32x16 accg[2], accu[2];
    #pragma unroll
    for (int i=0;i<16;++i){accg[0][i]=0.f;accg[1][i]=0.f;accu[0][i]=0.f;accu[1][i]=0.f;}

#define S1_STAGE_B(buf, kk) { \
    const ushort* bc = B1e + (size_t)(ks*32 + (kk))*8192; \
    gl16(bc + (2*w+0)*512 + ln*8, &Bb[buf][(2*w+0)*512]); \
    gl16(bc + (2*w+1)*512 + ln*8, &Bb[buf][(2*w+1)*512]); \
    gl16(bc + (8+2*w)*512 + ln*8, &Bb[buf][(8+2*w)*512]); \
    gl16(bc + (9+2*w)*512 + ln*8, &Bb[buf][(9+2*w)*512]); }

    // prologue: stage kk=0, prefetch A regs for kk=1
    {
        float4 va = *(const float4*)(asrc);
        float4 vb = *(const float4*)(asrc + 4);
        S1_STAGE_B(0, 0)
        short8 h8, l8; split8(va, vb, h8, l8);
        *(short8*)&Ab[0][fH*512 + lnA*8] = h8;
        *(short8*)&Ab[0][fL*512 + lnA*8] = l8;
    }
    float4 vaN = *(const float4*)(asrc + 32);
    float4 vbN = *(const float4*)(asrc + 36);

    int cur = 0;
    const int ro = ln*8;
    for (int kk = 0; kk < 32; ++kk) {
        __syncthreads();                 // buf[cur] ready; prev reads done
        if (kk + 1 < 32) {
            S1_STAGE_B(cur^1, kk+1)
            short8 h8, l8; split8(vaN, vbN, h8, l8);
            *(short8*)&Ab[cur^1][fH*512 + lnA*8] = h8;
            *(short8*)&Ab[cur^1][fL*512 + lnA*8] = l8;
            if (kk + 2 < 32) {
                vaN = *(const float4*)(asrc + (kk+2)*32);
                vbN = *(const float4*)(asrc + (kk+2)*32 + 4);
            }
        }
        #pragma unroll
        for (int kf = 0; kf < 2; ++kf) {
            short8 ah0 = *(const short8*)&Ab[cur][(0+kf)*512 + ro];
            short8 ah1 = *(const short8*)&Ab[cur][(2+kf)*512 + ro];
            short8 al0 = *(const short8*)&Ab[cur][(4+kf)*512 + ro];
            short8 al1 = *(const short8*)&Ab[cur][(6+kf)*512 + ro];
            short8 bg  = *(const short8*)&Bb[cur][(2*w+kf)*512 + ro];
            short8 bu  = *(const short8*)&Bb[cur][(8+2*w+kf)*512 + ro];
            accg[0]=MFMA(ah0,bg,accg[0]); accg[0]=MFMA(al0,bg,accg[0]);
            accg[1]=MFMA(ah1,bg,accg[1]); accg[1]=MFMA(al1,bg,accg[1]);
            accu[0]=MFMA(ah0,bu,accu[0]); accu[0]=MFMA(al0,bu,accu[0]);
            accu[1]=MFMA(ah1,bu,accu[1]); accu[1]=MFMA(al1,bu,accu[1]);
        }
        cur ^= 1;
    }
#undef S1_STAGE_B

    float* gp = gu + (size_t)ks*GU_PLANE;
    const int crhi = (ln>>5)*4, cl = ln&31;
    const int colg = x*128 + 32*w + cl;
    #pragma unroll
    for (int mi=0;mi<2;++mi)
      #pragma unroll
      for (int r=0;r<16;++r) {
        int row = mi*32 + (r&3) + 8*(r>>2) + crhi;
        if (m0 + row < cnt) {
            size_t base = (size_t)s_tk[row]*(2*INTER);
            gp[base + colg]         = accg[mi][r];
            gp[base + INTER + colg] = accu[mi][r];
        }
      }
}

// -------- fuse: h = silu(g0+g1)*(u0+u1) -> fragment-major A2 chunks (hi/lo) --
// A2 chunk (tile=e*8+y, k32 0..23): ushort[8*512]; f = p*4 + rg*2 + kf
__global__ __launch_bounds__(256)
void fuse_kernel(const float* __restrict__ gu, const int* __restrict__ counts,
                 const int* __restrict__ pair_tk, ushort* __restrict__ A2) {
    __shared__ int s_tk[64];
    const int tile = blockIdx.x;          // 128
    const int e = tile >> 3, y = tile & 7;
    const int cnt = min(counts[e], CAP);
    const int m0 = y*64;
    if (m0 >= cnt) return;
    const int tid = threadIdx.x;
    if (tid < 64) s_tk[tid] = pair_tk[e*CAP + min(m0+tid, cnt-1)];
    __syncthreads();

    const int s = tid >> 2, t4 = tid & 3;
    const int tk = s_tk[s];
    const float* g0 = gu + (size_t)tk*(2*INTER);
    const float* g1 = g0 + GU_PLANE;
    ushort* At = A2 + (size_t)tile*98304;
    const int rg = s >> 5, kf = t4 >> 1, oh = t4 & 1;
    const int ln2 = (s & 31) + 32*oh;
    const int fH = rg*2 + kf, fL = 4 + rg*2 + kf;

    for (int i = 0; i < 24; ++i) {
        int ko = i*32 + t4*8;
        float4 ga = *(const float4*)(g0 + ko);
        float4 gb = *(const float4*)(g0 + ko + 4);
        float4 gc = *(const float4*)(g1 + ko);
        float4 gd = *(const float4*)(g1 + ko + 4);
        float4 ua = *(const float4*)(g0 + INTER + ko);
        float4 ub = *(const float4*)(g0 + INTER + ko + 4);
        float4 uc = *(const float4*)(g1 + INTER + ko);
        float4 ud = *(const float4*)(g1 + INTER + ko + 4);
        float gg[8] = {ga.x+gc.x, ga.y+gc.y, ga.z+gc.z, ga.w+gc.w,
                       gb.x+gd.x, gb.y+gd.y, gb.z+gd.z, gb.w+gd.w};
        float uu[8] = {ua.x+uc.x, ua.y+uc.y, ua.z+uc.z, ua.w+uc.w,
                       ub.x+ud.x, ub.y+ud.y, ub.z+ud.z, ub.w+ud.w};
        float4 h0, h1;
        h0.x = gg[0]/(1.f+__expf(-gg[0]))*uu[0];
        h0.y = gg[1]/(1.f+__expf(-gg[1]))*uu[1];
        h0.z = gg[2]/(1.f+__expf(-gg[2]))*uu[2];
        h0.w = gg[3]/(1.f+__expf(-gg[3]))*uu[3];
        h1.x = gg[4]/(1.f+__expf(-gg[4]))*uu[4];
        h1.y = gg[5]/(1.f+__expf(-gg[5]))*uu[5];
        h1.z = gg[6]/(1.f+__expf(-gg[6]))*uu[6];
        h1.w = gg[7]/(1.f+__expf(-gg[7]))*uu[7];
        short8 h8, l8; split8(h0, h1, h8, l8);
        ushort* dst = At + (size_t)i*4096;
        *(short8*)&dst[fH*512 + ln2*8] = h8;
        *(short8*)&dst[fL*512 + ln2*8] = l8;
    }
}

// -------- stage2: BM=64, BN=256, BK=32, 24 steps, no K-split, all gl16 -------
__global__ __launch_bounds__(256, 3)
void s2mm_kernel(const ushort* __restrict__ A2, const ushort* __restrict__ B2,
                 const int* __restrict__ counts, const int* __restrict__ pair_tk,
                 const float* __restrict__ pair_w, float* __restrict__ ybuf) {
    __shared__ ushort Ab[2][8*512];
    __shared__ ushort Bb[2][16*512];
    __shared__ int   s_tk[64];
    __shared__ float s_w[64];

    const int lin  = blockIdx.x;                  // 1024 = 8*128
    const int work = (lin & 7)*128 + (lin >> 3);
    const int x = work & 7, y = (work >> 3) & 7, e = work >> 6;
    const int cnt = min(counts[e], CAP);
    const int m0 = y*64;
    if (m0 >= cnt) return;
    const int n0 = x*256;

    const int tid = threadIdx.x, ln = tid & 63, w = tid >> 6;
    if (tid < 64) {
        int sl = min(m0+tid, cnt-1);
        s_tk[tid] = pair_tk[e*CAP + sl];
        s_w[tid]  = pair_w [e*CAP + sl];
    }
    __syncthreads();

    const ushort* A2t = A2 + (size_t)(e*8 + y)*98304;
    const ushort* B2e = B2 + (size_t)(e*8 + x)*24*8192;

    f32x16 acc[2][2];
    #pragma unroll
    for (int mi=0;mi<2;++mi)
      #pragma unroll
      for (int ni=0;ni<2;++ni)
        #pragma unroll
        for (int i=0;i<16;++i) acc[mi][ni][i] = 0.f;

#define S2_STAGE(buf, k32) { \
    const ushort* ac = A2t + (size_t)(k32)*4096; \
    const ushort* bc = B2e + (size_t)(k32)*8192; \
    gl16(ac + (2*w+0)*512 + ln*8, &Ab[buf][(2*w+0)*512]); \
    gl16(ac + (2*w+1)*512 + ln*8, &Ab[buf][(2*w+1)*512]); \
    gl16(bc + (4*w+0)*512 + ln*8, &Bb[buf][(4*w+0)*512]); \
    gl16(bc + (4*w+1)*512 + ln*8, &Bb[buf][(4*w+1)*512]); \
    gl16(bc + (4*w+2)*512 + ln*8, &Bb[buf][(4*w+2)*512]); \
    gl16(bc + (4*w+3)*512 + ln*8, &Bb[buf][(4*w+3)*512]); }

    S2_STAGE(0, 0)
    int cur = 0;
    const int ro = ln*8;
    for (int k32 = 0; k32 < 24; ++k32) {
        __syncthreads();
        if (k32 + 1 < 24) S2_STAGE(cur^1, k32+1)
        #pragma unroll
        for (int kf = 0; kf < 2; ++kf) {
            short8 ah0 = *(const short8*)&Ab[cur][(0+kf)*512 + ro];
            short8 ah1 = *(const short8*)&Ab[cur][(2+kf)*512 + ro];
            short8 al0 = *(const short8*)&Ab[cur][(4+kf)*512 + ro];
            short8 al1 = *(const short8*)&Ab[cur][(6+kf)*512 + ro];
            short8 b0f = *(const short8*)&Bb[cur][(4*w+0+kf)*512 + ro];
            short8 b1f = *(const short8*)&Bb[cur][(4*w+2+kf)*512 + ro];
            acc[0][0]=MFMA(ah0,b0f,acc[0][0]); acc[0][0]=MFMA(al0,b0f,acc[0][0]);
            acc[1][0]=MFMA(ah1,b0f,acc[1][0]); acc[1][0]=MFMA(al1,b0f,acc[1][0]);
            acc[0][1]=MFMA(ah0,b1f,acc[0][1]); acc[0][1]=MFMA(al0,b1f,acc[0][1]);
            acc[1][1]=MFMA(ah1,b1f,acc[1][1]); acc[1][1]=MFMA(al1,b1f,acc[1][1]);
        }
        cur ^= 1;
    }
#undef S2_STAGE

    const int crhi = (ln>>5)*4, cl = ln&31;
    #pragma unroll
    for (int mi=0;mi<2;++mi)
      #pragma unroll
      for (int r=0;r<16;++r) {
        int row = mi*32 + (r&3) + 8*(r>>2) + crhi;
        if (m0 + row < cnt) {
            int   tk = s_tk[row];
            float wt = s_w[row];
            #pragma unroll
            for (int ni=0;ni<2;++ni) {
                int col = n0 + 64*w + 32*ni + cl;
                ybuf[(size_t)tk*HID + col] = wt*acc[mi][ni][r];
            }
        }
      }
}

// -------- combine: out[t] = y[2t] + y[2t+1] ----------------------------------
__global__ __launch_bounds__(256)
void combine_kernel(const float4* __restrict__ ybuf, float4* __restrict__ out) {
    int id = blockIdx.x*256 + threadIdx.x;       // T_TOK*HID/4 = 1048576
    int t = id >> 9, c = id & 511;
    float4 a = ybuf[(size_t)(2*t)*512 + c];
    float4 b = ybuf[(size_t)(2*t+1)*512 + c];
    out[id] = make_float4(a.x+b.x, a.y+b.y, a.z+b.z, a.w+b.w);
}

// ---------------- fallback path (round-4, measured-correct) ------------------
__global__ __launch_bounds__(256)
void fuse_fb_kernel(const float* __restrict__ gu, ushort* __restrict__ hhi,
                    ushort* __restrict__ hlo) {
    int id  = blockIdx.x*256 + threadIdx.x;
    int row = id / (INTER/4);
    int c4  = (id % (INTER/4)) * 4;
    const float* gr = gu + (size_t)row*(2*INTER) + c4;
    float4 g = *(const float4*)gr;
    float4 u = *(const float4*)(gr + INTER);
    float hv[4];
    hv[0] = g.x/(1.f+__expf(-g.x))*u.x;
    hv[1] = g.y/(1.f+__expf(-g.y))*u.y;
    hv[2] = g.z/(1.f+__expf(-g.z))*u.z;
    hv[3] = g.w/(1.f+__expf(-g.w))*u.w;
    ushort h0=bf16h(hv[0]), h1=bf16h(hv[1]), h2=bf16h(hv[2]), h3=bf16h(hv[3]);
    *(ushort4*)&hhi[(size_t)row*INTER + c4] = make_ushort4(h0,h1,h2,h3);
    *(ushort4*)&hlo[(size_t)row*INTER + c4] = make_ushort4(
        bf16h(hv[0]-__uint_as_float((uint32_t)h0<<16)),
        bf16h(hv[1]-__uint_as_float((uint32_t)h1<<16)),
        bf16h(hv[2]-__uint_as_float((uint32_t)h2<<16)),
        bf16h(hv[3]-__uint_as_float((uint32_t)h3<<16)));
}

__global__ __launch_bounds__(256)
void s1_fb_kernel(const float* __restrict__ hs, const float* __restrict__ gup,
                  const int* __restrict__ counts, const int* __restrict__ pair_tk,
                  float* __restrict__ gu) {
    __shared__ ushort Ahi[4*512], Alo[4*512];
    __shared__ ushort Bhi[16*512], Blo[16*512];
    __shared__ int s_tk[64];
    const int e  = blockIdx.z >> 1;
    const int ks = blockIdx.z & 1;
    const int cnt = min(counts[e], CAP);
    const int m0  = blockIdx.y * 64;
    if (m0 >= cnt) return;
    const int n0  = blockIdx.x * 128;
    const int tid = threadIdx.x, lane = tid & 63, w = tid >> 6;
    if (tid < 64) s_tk[tid] = pair_tk[e*CAP + min(m0+tid, cnt-1)];
    __syncthreads();
    const int ar = tid & 63, aq = tid >> 6;
    const float* asrc = hs + (size_t)(s_tk[ar] >> 1)*HID + ks*1024 + aq*8;
    const int br = tid;
    const float* bsrc = gup + (size_t)e*(2*INTER)*HID
                      + (size_t)((br < 128) ? (n0+br) : (INTER + n0 + br - 128))*HID + ks*1024;
    const int fA  = (ar>>5)*2 + (aq>>1);
    const int lnA = (ar&31) + 32*(aq&1);
    const int rgB = br >> 5, lnB = br & 31;
    f32x16 accg[2], accu[2];
    #pragma unroll
    for (int i=0;i<16;++i){ accg[0][i]=0.f; accg[1][i]=0.f; accu[0][i]=0.f; accu[1][i]=0.f; }
    float4 a0c,a1c,bvc[8], a0n,a1n,bvn[8];
    a0c = *(const float4*)(asrc + 0);
    a1c = *(const float4*)(asrc + 4);
    #pragma unroll
    for (int q=0;q<8;++q) bvc[q] = *(const float4*)(bsrc + 4*q);
#define S1_BODY(A0,A1,BV,A0N,A1N,BVN,KST)                                        \
    {                                                                            \
        __syncthreads();                                                         \
        { short8 h,l; split8(A0,A1,h,l);                                         \
          *(short8*)&Ahi[(fA<<9)+(lnA<<3)] = h;                                  \
          *(short8*)&Alo[(fA<<9)+(lnA<<3)] = l; }                                \
        _Pragma("unroll")                                                        \
        for (int o=0;o<4;++o) { short8 h,l; split8(BV[2*o],BV[2*o+1],h,l);       \
          int f = rgB*2 + (o>>1); int ln2 = lnB + 32*(o&1);                      \
          *(short8*)&Bhi[(f<<9)+(ln2<<3)] = h;                                   \
          *(short8*)&Blo[(f<<9)+(ln2<<3)] = l; }                                 \
        if ((KST)+1 < 32) {                                                     \
            int ko = ((KST)+1)*32;                                              \
            A0N = *(const float4*)(asrc + ko);                                  \
            A1N = *(const float4*)(asrc + ko + 4);                              \
            _Pragma("unroll")                                                   \
            for (int q=0;q<8;++q) BVN[q] = *(const float4*)(bsrc + ko + 4*q);   \
        }                                                                       \
        __syncthreads();                                                        \
        const int ro = lane << 3;                                               \
        _Pragma("unroll")                                                       \
        for (int kf=0;kf<2;++kf) {                                              \
            short8 ah0 = *(const short8*)&Ahi[((0*2+kf)<<9)+ro];                \
            short8 ah1 = *(const short8*)&Ahi[((1*2+kf)<<9)+ro];                \
            short8 al0 = *(const short8*)&Alo[((0*2+kf)<<9)+ro];                \
            short8 al1 = *(const short8*)&Alo[((1*2+kf)<<9)+ro];                \
            short8 bgh = *(const short8*)&Bhi[(((w  )*2+kf)<<9)+ro];            \
            short8 bgl = *(const short8*)&Blo[(((w  )*2+kf)<<9)+ro];            \
            short8 buh = *(const short8*)&Bhi[(((4+w)*2+kf)<<9)+ro];            \
            short8 bul = *(const short8*)&Blo[(((4+w)*2+kf)<<9)+ro];            \
            accg[0] = MFMA(ah0,bgh,accg[0]);                                    \
            accg[1] = MFMA(ah1,bgh,accg[1]);                                    \
            accu[0] = MFMA(ah0,buh,accu[0]);                                    \
            accu[1] = MFMA(ah1,buh,accu[1]);                                    \
            accg[0] = MFMA(al0,bgh,accg[0]);                                    \
            accg[1] = MFMA(al1,bgh,accg[1]);                                    \
            accu[0] = MFMA(al0,buh,accu[0]);                                    \
            accu[1] = MFMA(al1,buh,accu[1]);                                    \
            accg[0] = MFMA(ah0,bgl,accg[0]);                                    \
            accg[1] = MFMA(ah1,bgl,accg[1]);                                    \
            accu[0] = MFMA(ah0,bul,accu[0]);                                    \
            accu[1] = MFMA(ah1,bul,accu[1]);                                    \
        }                                                                       \
    }
    for (int kst = 0; kst < 32; kst += 2) {
        S1_BODY(a0c,a1c,bvc,a0n,a1n,bvn,kst)
        S1_BODY(a0n,a1n,bvn,a0c,a1c,bvc,kst+1)
    }
#undef S1_BODY
    const int crhi = (lane>>5)*4, cl = lane&31;
    const int colg = n0 + 32*w + cl;
    #pragma unroll
    for (int mi=0;mi<2;++mi)
      #pragma unroll
      for (int r=0;r<16;++r) {
        int row = mi*32 + (r&3) + 8*(r>>2) + crhi;
        if (m0 + row < cnt) {
            size_t base = (size_t)s_tk[row]*(2*INTER);
            atomicAdd(&gu[base + colg],         accg[mi][r]);
            atomicAdd(&gu[base + INTER + colg], accu[mi][r]);
        }
      }
}

__global__ __launch_bounds__(256)
void s2_fb_kernel(const ushort* __restrict__ hhi, const ushort* __restrict__ hlo,
                  const float* __restrict__ dwn, const int* __restrict__ counts,
                  const int* __restrict__ pair_tk, const float* __restrict__ pair_w,
                  float* __restrict__ out) {
    __shared__ ushort Ahi[4*512], Alo[4*512];
    __shared__ ushort Bhi[16*512], Blo[16*512];
    __shared__ int   s_tk[64];
    __shared__ float s_w[64];
    const int e  = blockIdx.z >> 1;
    const int ks = blockIdx.z & 1;
    const int cnt = min(counts[e], CAP);
    const int m0  = blockIdx.y * 64;
    if (m0 >= cnt) return;
    const int n0  = blockIdx.x * 256;
    const int tid = threadIdx.x, lane = tid & 63, w = tid >> 6;
    if (tid < 64) {
        int slot = min(m0+tid, cnt-1);
        s_tk[tid] = pair_tk[e*CAP + slot];
        s_w[tid]  = pair_w [e*CAP + slot];
    }
    __syncthreads();
    const int fA = tid >> 6, lnA = tid & 63;
    const int arow = (fA>>1)*32 + (lnA & 31);
    const int aoct = lnA >> 5, akf = fA & 1;
    const size_t aoff = (size_t)s_tk[arow]*INTER + ks*384 + akf*16 + aoct*8;
    const ushort* ahsrc = hhi + aoff;
    const ushort* alsrc = hlo + aoff;
    const int br = tid;
    const float* bsrc = dwn + (size_t)e*HID*INTER + (size_t)(n0+br)*INTER + ks*384;
    const int rgB = br >> 5, lnB = br & 31;
    f32x16 acc[2][2];
    #pragma unroll
    for (int mi=0;mi<2;++mi)
      #pragma unroll
      for (int ni=0;ni<2;++ni)
        #pragma unroll
        for (int i=0;i<16;++i) acc[mi][ni][i] = 0.f;
    short8 ahc, alc, ahn, aln;
    float4 bvc[8], bvn[8];
    ahc = *(const short8*)(ahsrc);
    alc = *(const short8*)(alsrc);
    #pragma unroll
    for (int q=0;q<8;++q) bvc[q] = *(const float4*)(bsrc + 4*q);
#define S2_BODY(AH,AL,BV,AHN,ALN,BVN,KST)                                        \
    {                                                                            \
        __syncthreads();                                                         \
        *(short8*)&Ahi[(fA<<9)+(lnA<<3)] = AH;                                   \
        *(short8*)&Alo[(fA<<9)+(lnA<<3)] = AL;                                   \
        _Pragma("unroll")                                                        \
        for (int o=0;o<4;++o) { short8 h,l; split8(BV[2*o],BV[2*o+1],h,l);       \
          int f = rgB*2 + (o>>1); int ln2 = lnB + 32*(o&1);                      \
          *(short8*)&Bhi[(f<<9)+(ln2<<3)] = h;                                   \
          *(short8*)&Blo[(f<<9)+(ln2<<3)] = l; }                                 \
        if ((KST)+1 < 12) {                                                     \
            int ko = ((KST)+1)*32;                                              \
            AHN = *(const short8*)(ahsrc + ko);                                 \
            ALN = *(const short8*)(alsrc + ko);                                 \
            _Pragma("unroll")                                                   \
            for (int q=0;q<8;++q) BVN[q] = *(const float4*)(bsrc + ko + 4*q);   \
        }                                                                       \
        __syncthreads();                                                        \
        const int ro = lane << 3;                                               \
        _Pragma("unroll")                                                       \
        for (int kf=0;kf<2;++kf) {                                              \
            short8 ah0 = *(const short8*)&Ahi[((0*2+kf)<<9)+ro];                \
            short8 ah1 = *(const short8*)&Ahi[((1*2+kf)<<9)+ro];                \
            short8 al0 = *(const short8*)&Alo[((0*2+kf)<<9)+ro];                \
            short8 al1 = *(const short8*)&Alo[((1*2+kf)<<9)+ro];                \
            _Pragma("unroll")                                                   \
            for (int ni=0;ni<2;++ni) {                                          \
                short8 bh = *(const short8*)&Bhi[(((2*w+ni)*2+kf)<<9)+ro];      \
                short8 bl = *(const short8*)&Blo[(((2*w+ni)*2+kf)<<9)+ro];      \
                acc[0][ni] = MFMA(ah0,bh,acc[0][ni]);                           \
                acc[1][ni] = MFMA(ah1,bh,acc[1][ni]);                           \
                acc[0][ni] = MFMA(al0,bh,acc[0][ni]);                           \
                acc[1][ni] = MFMA(al1,bh,acc[1][ni]);                           \
                acc[0][ni] = MFMA(ah0,bl,acc[0][ni]);                           \
                acc[1][ni] = MFMA(ah1,bl,acc[1][ni]);                           \
            }                                                                   \
        }                                                                       \
    }
    for (int kst = 0; kst < 12; kst += 2) {
        S2_BODY(ahc,alc,bvc,ahn,aln,bvn,kst)
        S2_BODY(ahn,aln,bvn,ahc,alc,bvc,kst+1)
    }
#undef S2_BODY
    const int crhi = (lane>>5)*4, cl = lane&31;
    #pragma unroll
    for (int mi=0;mi<2;++mi)
      #pragma unroll
      for (int r=0;r<16;++r) {
        int row = mi*32 + (r&3) + 8*(r>>2) + crhi;
        if (m0 + row < cnt) {
            int   t  = s_tk[row] >> 1;
            float wt = s_w[row];
            #pragma unroll
            for (int ni=0;ni<2;++ni) {
                int col = n0 + 64*w + 32*ni + cl;
                atomicAdd(&out[(size_t)t*HID + col], wt*acc[mi][ni][r]);
            }
        }
      }
}

extern "C" void kernel_launch(void* const* d_in, const int* in_sizes, int n_in,
                              void* d_out, int out_size, void* d_ws, size_t ws_size,
                              hipStream_t stream) {
    const float* hs  = (const float*)d_in[0];
    const int*   idx = (const int*)  d_in[1];
    const float* wts = (const float*)d_in[2];
    const float* gup = (const float*)d_in[3];
    const float* dwn = (const float*)d_in[4];
    float* out = (float*)d_out;

    char* ws = (char*)d_ws;
    int*   counts  = (int*)ws;
    int*   pair_tk = (int*)(ws + 1024);
    float* pair_w  = (float*)(ws + 1024 + NEXP*CAP*4);

    // fast-path layout with aliasing:
    //   [o_gu,  +50.3MB)  gu 2 planes  -> reused as B2 (same 50,331,648 bytes) after fuse
    //   [o_B1,  +100.7MB) B1 chunks    -> reused as A2 (25.2MB) + ybuf (33.5MB) after s1mm
    size_t o_gu  = 262144;
    size_t o_B1  = o_gu + 50331648;
    size_t need  = o_B1 + 100663296;     // ~144.3 MiB

    hipMemsetAsync(counts, 0, NEXP*sizeof(int), stream);
    route_kernel<<<(T_TOK*TOPK + 255)/256, 256, 0, stream>>>(idx, wts, counts, pair_tk, pair_w);

    if (ws_size >= need) {
        float*  gu   = (float*)(ws + o_gu);
        ushort* B1   = (ushort*)(ws + o_B1);
        ushort* B2   = (ushort*)(ws + o_gu);              // alias (after fuse)
        ushort* A2   = (ushort*)(ws + o_B1);              // alias (after s1mm)
        float*  ybuf = (float*)(ws + o_B1 + 25165824);    // alias (after s1mm)

        prep_s1B_kernel<<<4096, 256, 0, stream>>>(gup, B1);
        s1mm_kernel<<<1536, 256, 0, stream>>>(hs, B1, counts, pair_tk, gu);
        fuse_kernel<<<128, 256, 0, stream>>>(gu, counts, pair_tk, A2);
        prep_s2B_kernel<<<4096, 256, 0, stream>>>(dwn, B2);
        s2mm_kernel<<<1024, 256, 0, stream>>>(A2, B2, counts, pair_tk, pair_w, ybuf);
        combine_kernel<<<(T_TOK*HID/4)/256, 256, 0, stream>>>((const float4*)ybuf, (float4*)out);
    } else {
        // round-4 fallback (~38 MB)
        float*  gu  = (float*)(ws + 262144);
        ushort* hhi = (ushort*)(ws + 262144 + 25165824);
        ushort* hlo = (ushort*)(ws + 262144 + 25165824 + 6291456);
        hipMemsetAsync(gu, 0, (size_t)T_TOK*TOPK*2*INTER*4, stream);
        hipMemsetAsync(out, 0, (size_t)T_TOK*HID*sizeof(float), stream);
        s1_fb_kernel<<<dim3(INTER/128, MBLK, NEXP*2), 256, 0, stream>>>(hs, gup, counts,
                                                                        pair_tk, gu);
        fuse_fb_kernel<<<(T_TOK*TOPK*INTER/4)/256, 256, 0, stream>>>(gu, hhi, hlo);
        s2_fb_kernel<<<dim3(HID/256, MBLK, NEXP*2), 256, 0, stream>>>(hhi, hlo, dwn, counts,
                                                                      pair_tk, pair_w, out);
    }
}